// Round 1
// baseline (22840.263 us; speedup 1.0000x reference)
//
#include <hip/hip_runtime.h>
#include <hip/hip_bf16.h>

#define DEVINL __device__ __forceinline__

// ---------------------------------------------------------------------------
// Direct Conv2d, stride 1, symmetric pad, input = concat(in1[C1], in2[C2]).
// One thread per output element (b, co, y, x), flattened x-major.
// ---------------------------------------------------------------------------
template<int K>
__global__ void conv2d_direct(const float* __restrict__ in1, int C1,
                              const float* __restrict__ in2, int C2,
                              const float* __restrict__ w,
                              const float* __restrict__ bias,
                              float* __restrict__ out,
                              int B, int H, int W, int Cout) {
    constexpr int P = K / 2;
    int idx = blockIdx.x * blockDim.x + threadIdx.x;
    int total = B * Cout * H * W;
    if (idx >= total) return;
    int x  = idx % W;
    int y  = (idx / W) % H;
    int co = (idx / (W * H)) % Cout;
    int b  = idx / (W * H * Cout);

    const int Cin = C1 + C2;
    float acc = bias[co];
    const float* wco = w + (size_t)co * Cin * K * K;

    for (int ci = 0; ci < Cin; ++ci) {
        const float* src = (ci < C1)
            ? (in1 + ((size_t)(b * C1 + ci)) * H * W)
            : (in2 + ((size_t)(b * C2 + (ci - C1))) * H * W);
        const float* wc = wco + ci * K * K;
        #pragma unroll
        for (int ky = 0; ky < K; ++ky) {
            int iy = y + ky - P;
            if (iy < 0 || iy >= H) continue;
            const float* row = src + (size_t)iy * W;
            #pragma unroll
            for (int kx = 0; kx < K; ++kx) {
                int ix = x + kx - P;
                if (ix < 0 || ix >= W) continue;
                acc = fmaf(row[ix], wc[ky * K + kx], acc);
            }
        }
    }
    out[idx] = acc;
}

// ---------------------------------------------------------------------------
// ConvTranspose2d k=3, stride=2, pad=1, output_pad=1, no bias.
// wt layout: (Cin, Cout, 3, 3)  (torch ConvTranspose2d weight layout)
// out[b,co,oy,ox] = sum_{ci,ky,kx valid} in[b,ci,(oy+1-ky)/2,(ox+1-kx)/2]*wt[ci,co,ky,kx]
// ---------------------------------------------------------------------------
__global__ void convt2x_k3(const float* __restrict__ in,
                           const float* __restrict__ wt,
                           float* __restrict__ out,
                           int B, int Cin, int Cout, int Hin, int Win) {
    int Ho = 2 * Hin, Wo = 2 * Win;
    int idx = blockIdx.x * blockDim.x + threadIdx.x;
    int total = B * Cout * Ho * Wo;
    if (idx >= total) return;
    int ox = idx % Wo;
    int oy = (idx / Wo) % Ho;
    int co = (idx / (Wo * Ho)) % Cout;
    int b  = idx / (Wo * Ho * Cout);

    int iys[2], kys[2], nky = 0;
    int ixs[2], kxs[2], nkx = 0;
    #pragma unroll
    for (int k = 0; k < 3; ++k) {
        int ty = oy + 1 - k;
        if ((ty & 1) == 0) { int iy = ty >> 1; if (iy >= 0 && iy < Hin) { iys[nky] = iy; kys[nky] = k; ++nky; } }
        int tx = ox + 1 - k;
        if ((tx & 1) == 0) { int ix = tx >> 1; if (ix >= 0 && ix < Win) { ixs[nkx] = ix; kxs[nkx] = k; ++nkx; } }
    }

    float acc = 0.f;
    for (int ci = 0; ci < Cin; ++ci) {
        const float* src = in + ((size_t)(b * Cin + ci)) * Hin * Win;
        const float* wb  = wt + ((size_t)ci * Cout + co) * 9;
        for (int a = 0; a < nky; ++a) {
            const float* row = src + (size_t)iys[a] * Win;
            const float* wr  = wb + kys[a] * 3;
            for (int c = 0; c < nkx; ++c)
                acc = fmaf(row[ixs[c]], wr[kxs[c]], acc);
        }
    }
    out[idx] = acc;
}

// ---------------------------------------------------------------------------
// InstanceNorm stats: one block per (b,c). Biased variance, eps=1e-5.
// ---------------------------------------------------------------------------
__global__ void inorm_stats(const float* __restrict__ x,
                            float* __restrict__ mean,
                            float* __restrict__ istd, int HW) {
    int bc = blockIdx.x;
    const float* p = x + (size_t)bc * HW;
    float s = 0.f, ss = 0.f;
    for (int i = threadIdx.x; i < HW; i += blockDim.x) {
        float v = p[i];
        s += v; ss += v * v;
    }
    #pragma unroll
    for (int o = 32; o > 0; o >>= 1) {
        s  += __shfl_down(s, o);
        ss += __shfl_down(ss, o);
    }
    __shared__ float sh[4][2];
    int wid = threadIdx.x >> 6, lane = threadIdx.x & 63;
    if (lane == 0) { sh[wid][0] = s; sh[wid][1] = ss; }
    __syncthreads();
    if (threadIdx.x == 0) {
        float S = 0.f, SS = 0.f;
        for (int i = 0; i < 4; ++i) { S += sh[i][0]; SS += sh[i][1]; }
        float m = S / HW;
        float v = SS / HW - m * m;
        v = v > 0.f ? v : 0.f;
        mean[bc] = m;
        istd[bc] = rsqrtf(v + 1e-5f);
    }
}

// ---------------------------------------------------------------------------
// finish (no residual): out = relu((raw - m) * istd)
// ---------------------------------------------------------------------------
__global__ void finish_plain(const float* __restrict__ raw,
                             const float* __restrict__ mean,
                             const float* __restrict__ istd,
                             float* __restrict__ out,
                             int B, int Cout, int HW) {
    int idx = blockIdx.x * blockDim.x + threadIdx.x;
    int total = B * Cout * HW;
    if (idx >= total) return;
    int bc = idx / HW;
    float v = (raw[idx] - mean[bc]) * istd[bc];
    out[idx] = v > 0.f ? v : 0.f;
}

// ---------------------------------------------------------------------------
// finish + residual 1x1 conv: out = relu((raw-m)*istd) + (wr @ fsrc + br)
// fsrc has Cf=256 channels.
// ---------------------------------------------------------------------------
__global__ void finish_res(const float* __restrict__ raw,
                           const float* __restrict__ mean,
                           const float* __restrict__ istd,
                           const float* __restrict__ fsrc, int Cf,
                           const float* __restrict__ wr,
                           const float* __restrict__ br,
                           float* __restrict__ out,
                           int B, int Cout, int H, int W) {
    int idx = blockIdx.x * blockDim.x + threadIdx.x;
    int total = B * Cout * H * W;
    if (idx >= total) return;
    int x  = idx % W;
    int y  = (idx / W) % H;
    int co = (idx / (W * H)) % Cout;
    int b  = idx / (W * H * Cout);
    int bc = b * Cout + co;

    float v = (raw[idx] - mean[bc]) * istd[bc];
    v = v > 0.f ? v : 0.f;

    float acc = br[co];
    const float* f  = fsrc + ((size_t)b * Cf) * H * W + (size_t)y * W + x;
    const float* wc = wr + (size_t)co * Cf;
    size_t cs = (size_t)H * W;
    for (int ci = 0; ci < Cf; ++ci)
        acc = fmaf(f[(size_t)ci * cs], wc[ci], acc);

    out[idx] = v + acc;
}

static inline int cdiv(int a, int b) { return (a + b - 1) / b; }

extern "C" void kernel_launch(void* const* d_in, const int* in_sizes, int n_in,
                              void* d_out, int out_size, void* d_ws, size_t ws_size,
                              hipStream_t stream) {
    const float* f4   = (const float*)d_in[0];
    const float* f8   = (const float*)d_in[1];
    const float* f16  = (const float*)d_in[2];
    const float* f32  = (const float*)d_in[3];
    const float* w32  = (const float*)d_in[4];
    const float* b32  = (const float*)d_in[5];
    const float* wt32 = (const float*)d_in[6];
    const float* w16  = (const float*)d_in[7];
    const float* b16  = (const float*)d_in[8];
    const float* wr16 = (const float*)d_in[9];
    const float* br16 = (const float*)d_in[10];
    const float* wt16 = (const float*)d_in[11];
    const float* w8   = (const float*)d_in[12];
    const float* b8   = (const float*)d_in[13];
    const float* wr8  = (const float*)d_in[14];
    const float* br8  = (const float*)d_in[15];
    const float* wt8  = (const float*)d_in[16];
    const float* w4   = (const float*)d_in[17];
    const float* b4   = (const float*)d_in[18];
    const float* wr4  = (const float*)d_in[19];
    const float* br4  = (const float*)d_in[20];

    float* out = (float*)d_out;

    const int B = 2, C = 256;
    const int H4 = 160, W4 = 240;
    const int H8 = 80,  W8 = 120;
    const int H16 = 40, W16 = 60;
    const int H32 = 20, W32 = 30;

    // d_out layout: feat4 | feat8 | feat16 | feat32
    float* feat4  = out;
    float* feat8  = out + (size_t)B * 48 * H4 * W4;
    float* feat16 = feat8 + (size_t)B * 64 * H8 * W8;
    float* feat32 = feat16 + (size_t)B * 192 * H16 * W16;

    // workspace: A (up buffer) | Braw (raw conv out) | stats
    const size_t bufElems = (size_t)B * 48 * H4 * W4; // 3,686,400 (max of both)
    float* wsA   = (float*)d_ws;
    float* wsRaw = wsA + bufElems;
    float* stMean = wsRaw + bufElems;
    float* stIstd = stMean + 512;

    const int T = 256;

    // ---- stage 32 ----
    {
        int tot = B * 160 * H32 * W32;
        conv2d_direct<3><<<cdiv(tot, T), T, 0, stream>>>(f32, C, nullptr, 0, w32, b32,
                                                         wsRaw, B, H32, W32, 160);
        inorm_stats<<<B * 160, T, 0, stream>>>(wsRaw, stMean, stIstd, H32 * W32);
        finish_plain<<<cdiv(tot, T), T, 0, stream>>>(wsRaw, stMean, stIstd, feat32,
                                                     B, 160, H32 * W32);
        int totu = B * 192 * H16 * W16;
        convt2x_k3<<<cdiv(totu, T), T, 0, stream>>>(feat32, wt32, wsA, B, 160, 192, H32, W32);
    }
    // ---- stage 16 ----
    {
        int tot = B * 192 * H16 * W16;
        conv2d_direct<5><<<cdiv(tot, T), T, 0, stream>>>(f16, C, wsA, 192, w16, b16,
                                                         wsRaw, B, H16, W16, 192);
        inorm_stats<<<B * 192, T, 0, stream>>>(wsRaw, stMean, stIstd, H16 * W16);
        finish_res<<<cdiv(tot, T), T, 0, stream>>>(wsRaw, stMean, stIstd, f16, C,
                                                   wr16, br16, feat16, B, 192, H16, W16);
        int totu = B * 64 * H8 * W8;
        convt2x_k3<<<cdiv(totu, T), T, 0, stream>>>(feat16, wt16, wsA, B, 192, 64, H16, W16);
    }
    // ---- stage 8 ----
    {
        int tot = B * 64 * H8 * W8;
        conv2d_direct<5><<<cdiv(tot, T), T, 0, stream>>>(f8, C, wsA, 64, w8, b8,
                                                         wsRaw, B, H8, W8, 64);
        inorm_stats<<<B * 64, T, 0, stream>>>(wsRaw, stMean, stIstd, H8 * W8);
        finish_res<<<cdiv(tot, T), T, 0, stream>>>(wsRaw, stMean, stIstd, f8, C,
                                                   wr8, br8, feat8, B, 64, H8, W8);
        int totu = B * 48 * H4 * W4;
        convt2x_k3<<<cdiv(totu, T), T, 0, stream>>>(feat8, wt8, wsA, B, 64, 48, H8, W8);
    }
    // ---- stage 4 ----
    {
        int tot = B * 48 * H4 * W4;
        conv2d_direct<5><<<cdiv(tot, T), T, 0, stream>>>(f4, C, wsA, 48, w4, b4,
                                                         wsRaw, B, H4, W4, 48);
        inorm_stats<<<B * 48, T, 0, stream>>>(wsRaw, stMean, stIstd, H4 * W4);
        finish_res<<<cdiv(tot, T), T, 0, stream>>>(wsRaw, stMean, stIstd, f4, C,
                                                   wr4, br4, feat4, B, 48, H4, W4);
    }
}

// Round 2
// 4781.734 us; speedup vs baseline: 4.7766x; 4.7766x over previous
//
#include <hip/hip_runtime.h>
#include <hip/hip_bf16.h>

static inline int cdiv(int a, int b) { return (a + b - 1) / b; }

// ---------------------------------------------------------------------------
// Tiled direct Conv2d, stride 1, pad K/2, input = concat(in1[C1], in2[C2]).
// Block: 256 threads = 4 waves. Lane -> 8x8 spatial grid (sx=lane&7, sy=lane>>3),
// wave -> CO_PER output channels. Tile = (PH*8) x (PW*8) spatial x (4*CO_PER) couts.
// Cin staged in chunks of CI_CHUNK through LDS. Optional fused 1x1 residual conv
// (center tap, first C1 channels) accumulated separately -> outRes.
// Main-conv bias omitted on purpose: InstanceNorm cancels it.
// ---------------------------------------------------------------------------
template<int K, int PH, int PW, int CO_PER, bool HAS_RES, int CI_CHUNK>
__global__ __launch_bounds__(256)
void conv_tiled(const float* __restrict__ in1, int C1,
                const float* __restrict__ in2, int C2,
                const float* __restrict__ w,
                const float* __restrict__ wr,
                float* __restrict__ outRaw,
                float* __restrict__ outRes,
                int H, int W, int Cout, int tilesX) {
    constexpr int TH = PH * 8, TW = PW * 8;
    constexpr int P = K / 2;
    constexpr int PR = TH + K - 1;         // patch rows
    constexpr int PC = TW + K - 1;         // patch cols (valid)
    constexpr int ROWF = (PW + K - 1 + 3) & ~3;  // per-thread row floats (padded to x4)
    constexpr int PCP = 7 * PW + ROWF + 4; // padded LDS row stride (16B-aligned reads fit)
    constexpr int KK = K * K;
    constexpr int KKP = (KK + 3) & ~3;
    constexpr int CO_BLK = 4 * CO_PER;

    __shared__ float sIn[CI_CHUNK][PR][PCP];
    __shared__ float sW[CI_CHUNK][CO_BLK][KKP];
    __shared__ float sWr[HAS_RES ? CI_CHUNK : 1][CO_BLK];

    const int tid = threadIdx.x;
    const int lane = tid & 63, wv = tid >> 6;
    const int sx = lane & 7, sy = lane >> 3;
    const int tileX = blockIdx.x % tilesX, tileY = blockIdx.x / tilesX;
    const int b = blockIdx.z, coChunk = blockIdx.y;
    const int Cin = C1 + C2;
    const int x0 = tileX * TW, y0 = tileY * TH;
    const int ix0 = x0 - P, iy0 = y0 - P;
    const size_t HW = (size_t)H * W;

    float acc[PH][PW][CO_PER];
    #pragma unroll
    for (int a = 0; a < PH; ++a)
        #pragma unroll
        for (int c = 0; c < PW; ++c)
            #pragma unroll
            for (int j = 0; j < CO_PER; ++j) acc[a][c][j] = 0.f;

    float accR[HAS_RES ? PH : 1][HAS_RES ? PW : 1][HAS_RES ? CO_PER : 1];
    if (HAS_RES) {
        #pragma unroll
        for (int a = 0; a < (HAS_RES ? PH : 1); ++a)
            #pragma unroll
            for (int c = 0; c < (HAS_RES ? PW : 1); ++c)
                #pragma unroll
                for (int j = 0; j < (HAS_RES ? CO_PER : 1); ++j) accR[a][c][j] = 0.f;
    }

    for (int ci0 = 0; ci0 < Cin; ci0 += CI_CHUNK) {
        __syncthreads();
        // ---- stage input patch (zero-padded borders) ----
        constexpr int NIN = CI_CHUNK * PR * PC;
        for (int i = tid; i < NIN; i += 256) {
            int c = i % PC;
            int rc = i / PC;
            int r = rc % PR;
            int cc = rc / PR;
            int ci = ci0 + cc;
            int gy = iy0 + r, gx = ix0 + c;
            float v = 0.f;
            if ((unsigned)gy < (unsigned)H && (unsigned)gx < (unsigned)W) {
                const float* src;
                int cl;
                if (ci < C1) { src = in1; cl = b * C1 + ci; }
                else         { src = in2; cl = b * C2 + (ci - C1); }
                v = src[(size_t)cl * HW + (size_t)gy * W + gx];
            }
            sIn[cc][r][c] = v;
        }
        // ---- stage weights (zero-pad KK..KKP) ----
        constexpr int NW = CI_CHUNK * CO_BLK * KKP;
        for (int i = tid; i < NW; i += 256) {
            int t = i % KKP;
            int rc = i / KKP;
            int coi = rc % CO_BLK;
            int cc = rc / CO_BLK;
            float v = 0.f;
            if (t < KK)
                v = w[((size_t)(coChunk * CO_BLK + coi) * Cin + (ci0 + cc)) * KK + t];
            sW[cc][coi][t] = v;
        }
        if (HAS_RES) {
            for (int i = tid; i < CI_CHUNK * CO_BLK; i += 256) {
                int coi = i % CO_BLK, cc = i / CO_BLK;
                int ci = ci0 + cc;
                sWr[cc][coi] = (ci < C1) ? wr[(size_t)(coChunk * CO_BLK + coi) * C1 + ci] : 0.f;
            }
        }
        __syncthreads();
        // ---- compute ----
        for (int cc = 0; cc < CI_CHUNK; ++cc) {
            // per-thread input patch into registers (float4 loads, 16B aligned)
            float xw[PH + K - 1][ROWF];
            #pragma unroll
            for (int r = 0; r < PH + K - 1; ++r)
                #pragma unroll
                for (int q = 0; q < ROWF / 4; ++q)
                    *(float4*)&xw[r][q * 4] = *(const float4*)&sIn[cc][sy * PH + r][sx * PW + q * 4];

            #pragma unroll
            for (int j = 0; j < CO_PER; ++j) {
                const float* wrow = &sW[cc][wv * CO_PER + j][0];
                #pragma unroll
                for (int tg = 0; tg < KKP / 4; ++tg) {
                    float w4[4];
                    *(float4*)w4 = *(const float4*)&wrow[tg * 4];
                    #pragma unroll
                    for (int u = 0; u < 4; ++u) {
                        int t = tg * 4 + u;
                        if (t < KK) {
                            int ky = t / K, kx = t % K;
                            float wv_ = w4[u];
                            #pragma unroll
                            for (int py = 0; py < PH; ++py)
                                #pragma unroll
                                for (int px = 0; px < PW; ++px)
                                    acc[py][px][j] = fmaf(xw[py + ky][px + kx], wv_, acc[py][px][j]);
                        }
                    }
                }
                if (HAS_RES) {
                    float wres = sWr[cc][wv * CO_PER + j];  // zero for ci >= C1
                    #pragma unroll
                    for (int py = 0; py < PH; ++py)
                        #pragma unroll
                        for (int px = 0; px < PW; ++px)
                            accR[py][px][j] = fmaf(xw[py + P][px + P], wres, accR[py][px][j]);
                }
            }
        }
    }

    // ---- store ----
    const int coB = coChunk * CO_BLK + wv * CO_PER;
    #pragma unroll
    for (int j = 0; j < CO_PER; ++j) {
        #pragma unroll
        for (int py = 0; py < PH; ++py) {
            int y = y0 + sy * PH + py;
            if (y >= H) continue;
            #pragma unroll
            for (int px = 0; px < PW; ++px) {
                int x = x0 + sx * PW + px;
                if (x >= W) continue;
                size_t o = ((size_t)(b * Cout + coB + j)) * HW + (size_t)y * W + x;
                outRaw[o] = acc[py][px][j];
                if (HAS_RES) outRes[o] = accR[py][px][j];
            }
        }
    }
}

// ---------------------------------------------------------------------------
// ConvTranspose2d k=3, stride=2, pad=1, output_pad=1, no bias.
// Grid: (pxChunks, Cout, B). Per-co weights staged in LDS.
// ---------------------------------------------------------------------------
__global__ __launch_bounds__(256)
void convt2x_k3(const float* __restrict__ in,
                const float* __restrict__ wt,
                float* __restrict__ out,
                int Cin, int Cout, int Hin, int Win) {
    extern __shared__ float wlds[];  // Cin*9
    const int co = blockIdx.y, b = blockIdx.z;
    for (int i = threadIdx.x; i < Cin * 9; i += 256)
        wlds[i] = wt[(size_t)(i / 9) * Cout * 9 + (size_t)co * 9 + (i % 9)];
    __syncthreads();

    const int Ho = 2 * Hin, Wo = 2 * Win;
    const int HWo = Ho * Wo, HWi = Hin * Win;
    const float* inb = in + (size_t)b * Cin * HWi;
    float* ob = out + ((size_t)(b * Cout + co)) * HWo;

    #pragma unroll
    for (int k = 0; k < 4; ++k) {
        int px = blockIdx.x * 1024 + k * 256 + threadIdx.x;
        if (px >= HWo) continue;
        int ox = px % Wo, oy = px / Wo;
        int iys[2], kys[2], nky = 0;
        int ixs[2], kxs[2], nkx = 0;
        #pragma unroll
        for (int t = 0; t < 3; ++t) {
            int ty = oy + 1 - t;
            if (!(ty & 1)) { int iy = ty >> 1; if ((unsigned)iy < (unsigned)Hin) { iys[nky] = iy; kys[nky] = t; ++nky; } }
            int tx = ox + 1 - t;
            if (!(tx & 1)) { int ix = tx >> 1; if ((unsigned)ix < (unsigned)Win) { ixs[nkx] = ix; kxs[nkx] = t; ++nkx; } }
        }
        float acc = 0.f;
        for (int ci = 0; ci < Cin; ++ci) {
            const float* src = inb + (size_t)ci * HWi;
            const float* wc = &wlds[ci * 9];
            for (int a = 0; a < nky; ++a) {
                int rb = iys[a] * Win, wb = kys[a] * 3;
                for (int c2 = 0; c2 < nkx; ++c2)
                    acc = fmaf(src[rb + ixs[c2]], wc[wb + kxs[c2]], acc);
            }
        }
        ob[px] = acc;
    }
}

// ---------------------------------------------------------------------------
// InstanceNorm stats: one block per (b,c). Biased variance, eps=1e-5.
// ---------------------------------------------------------------------------
__global__ __launch_bounds__(256)
void inorm_stats(const float* __restrict__ x,
                 float* __restrict__ mean,
                 float* __restrict__ istd, int HW) {
    int bc = blockIdx.x;
    const float4* p = (const float4*)(x + (size_t)bc * HW);
    int n4 = HW >> 2;
    float s = 0.f, ss = 0.f;
    for (int i = threadIdx.x; i < n4; i += 256) {
        float4 v = p[i];
        s += v.x + v.y + v.z + v.w;
        ss += v.x * v.x + v.y * v.y + v.z * v.z + v.w * v.w;
    }
    #pragma unroll
    for (int o = 32; o > 0; o >>= 1) {
        s  += __shfl_down(s, o);
        ss += __shfl_down(ss, o);
    }
    __shared__ float sh[4][2];
    int wid = threadIdx.x >> 6, ln = threadIdx.x & 63;
    if (ln == 0) { sh[wid][0] = s; sh[wid][1] = ss; }
    __syncthreads();
    if (threadIdx.x == 0) {
        float S = 0.f, SS = 0.f;
        for (int i = 0; i < 4; ++i) { S += sh[i][0]; SS += sh[i][1]; }
        float m = S / HW;
        float v = SS / HW - m * m;
        v = v > 0.f ? v : 0.f;
        mean[bc] = m;
        istd[bc] = rsqrtf(v + 1e-5f);
    }
}

// ---------------------------------------------------------------------------
// Epilogue: feat = relu((raw - m)*istd) [+ feat(res) + br[co]]
// float4 vectorized; HW is a multiple of 4, so all 4 elems share (b,c).
// ---------------------------------------------------------------------------
template<bool HAS_RES>
__global__ __launch_bounds__(256)
void epilogue_k(const float* __restrict__ raw,
                const float* __restrict__ mean,
                const float* __restrict__ istd,
                const float* __restrict__ br,
                float* __restrict__ feat,
                int HW, int Cout, int total4) {
    int i = blockIdx.x * 256 + threadIdx.x;
    if (i >= total4) return;
    int bc = (int)(((long long)i * 4) / HW);
    float m = mean[bc], is = istd[bc];
    float4 r = ((const float4*)raw)[i];
    float4 o;
    o.x = fmaxf((r.x - m) * is, 0.f);
    o.y = fmaxf((r.y - m) * is, 0.f);
    o.z = fmaxf((r.z - m) * is, 0.f);
    o.w = fmaxf((r.w - m) * is, 0.f);
    if (HAS_RES) {
        float bb = br[bc % Cout];
        float4 e = ((float4*)feat)[i];
        o.x += e.x + bb; o.y += e.y + bb; o.z += e.z + bb; o.w += e.w + bb;
    }
    ((float4*)feat)[i] = o;
}

extern "C" void kernel_launch(void* const* d_in, const int* in_sizes, int n_in,
                              void* d_out, int out_size, void* d_ws, size_t ws_size,
                              hipStream_t stream) {
    const float* f4   = (const float*)d_in[0];
    const float* f8   = (const float*)d_in[1];
    const float* f16  = (const float*)d_in[2];
    const float* f32  = (const float*)d_in[3];
    const float* w32  = (const float*)d_in[4];
    const float* wt32 = (const float*)d_in[6];
    const float* w16  = (const float*)d_in[7];
    const float* wr16 = (const float*)d_in[9];
    const float* br16 = (const float*)d_in[10];
    const float* wt16 = (const float*)d_in[11];
    const float* w8   = (const float*)d_in[12];
    const float* wr8  = (const float*)d_in[14];
    const float* br8  = (const float*)d_in[15];
    const float* wt8  = (const float*)d_in[16];
    const float* w4   = (const float*)d_in[17];
    const float* wr4  = (const float*)d_in[19];
    const float* br4  = (const float*)d_in[20];
    // main-conv biases (d_in[5,8,13,18]) cancel under InstanceNorm -> unused.

    float* out = (float*)d_out;

    const int B = 2, C = 256;
    const int H4 = 160, W4 = 240;
    const int H8 = 80,  W8 = 120;
    const int H16 = 40, W16 = 60;
    const int H32 = 20, W32 = 30;

    float* feat4  = out;
    float* feat8  = out + (size_t)B * 48 * H4 * W4;
    float* feat16 = feat8 + (size_t)B * 64 * H8 * W8;
    float* feat32 = feat16 + (size_t)B * 192 * H16 * W16;

    const size_t bufElems = (size_t)B * 48 * H4 * W4;  // 3,686,400
    float* wsA    = (float*)d_ws;        // upsampled map
    float* wsRaw  = wsA + bufElems;      // raw conv output
    float* stMean = wsRaw + bufElems;
    float* stIstd = stMean + 512;

    // ---------------- stage 32 (K=3, Cin=256, Cout=160, 20x30) ----------------
    {
        int tilesX = cdiv(W32, 32), tilesY = cdiv(H32, 8);
        dim3 g(tilesX * tilesY, 160 / 16, B);
        conv_tiled<3, 1, 4, 4, false, 4><<<g, 256, 0, stream>>>(
            f32, C, nullptr, 0, w32, nullptr, wsRaw, nullptr, H32, W32, 160, tilesX);
        inorm_stats<<<B * 160, 256, 0, stream>>>(wsRaw, stMean, stIstd, H32 * W32);
        int tot4 = B * 160 * H32 * W32 / 4;
        epilogue_k<false><<<cdiv(tot4, 256), 256, 0, stream>>>(
            wsRaw, stMean, stIstd, nullptr, feat32, H32 * W32, 160, tot4);
        int HWo = (2 * H32) * (2 * W32);
        dim3 gu(cdiv(HWo, 1024), 192, B);
        convt2x_k3<<<gu, 256, 160 * 9 * 4, stream>>>(feat32, wt32, wsA, 160, 192, H32, W32);
    }
    // ---------------- stage 16 (K=5, Cin=256+192, Cout=192, 40x60) ------------
    {
        int tilesX = cdiv(W16, 32), tilesY = cdiv(H16, 8);
        dim3 g(tilesX * tilesY, 192 / 16, B);
        conv_tiled<5, 1, 4, 4, true, 4><<<g, 256, 0, stream>>>(
            f16, C, wsA, 192, w16, wr16, wsRaw, feat16, H16, W16, 192, tilesX);
        inorm_stats<<<B * 192, 256, 0, stream>>>(wsRaw, stMean, stIstd, H16 * W16);
        int tot4 = B * 192 * H16 * W16 / 4;
        epilogue_k<true><<<cdiv(tot4, 256), 256, 0, stream>>>(
            wsRaw, stMean, stIstd, br16, feat16, H16 * W16, 192, tot4);
        int HWo = (2 * H16) * (2 * W16);
        dim3 gu(cdiv(HWo, 1024), 64, B);
        convt2x_k3<<<gu, 256, 192 * 9 * 4, stream>>>(feat16, wt16, wsA, 192, 64, H16, W16);
    }
    // ---------------- stage 8 (K=5, Cin=256+64, Cout=64, 80x120) --------------
    {
        int tilesX = cdiv(W8, 32), tilesY = cdiv(H8, 16);
        dim3 g(tilesX * tilesY, 64 / 8, B);
        conv_tiled<5, 2, 4, 2, true, 4><<<g, 256, 0, stream>>>(
            f8, C, wsA, 64, w8, wr8, wsRaw, feat8, H8, W8, 64, tilesX);
        inorm_stats<<<B * 64, 256, 0, stream>>>(wsRaw, stMean, stIstd, H8 * W8);
        int tot4 = B * 64 * H8 * W8 / 4;
        epilogue_k<true><<<cdiv(tot4, 256), 256, 0, stream>>>(
            wsRaw, stMean, stIstd, br8, feat8, H8 * W8, 64, tot4);
        int HWo = (2 * H8) * (2 * W8);
        dim3 gu(cdiv(HWo, 1024), 48, B);
        convt2x_k3<<<gu, 256, 64 * 9 * 4, stream>>>(feat8, wt8, wsA, 64, 48, H8, W8);
    }
    // ---------------- stage 4 (K=5, Cin=256+48, Cout=48, 160x240) -------------
    {
        int tilesX = cdiv(W4, 32), tilesY = cdiv(H4, 32);
        dim3 g(tilesX * tilesY, 48 / 8, B);
        conv_tiled<5, 4, 4, 2, true, 4><<<g, 256, 0, stream>>>(
            f4, C, wsA, 48, w4, wr4, wsRaw, feat4, H4, W4, 48, tilesX);
        inorm_stats<<<B * 48, 256, 0, stream>>>(wsRaw, stMean, stIstd, H4 * W4);
        int tot4 = B * 48 * H4 * W4 / 4;
        epilogue_k<true><<<cdiv(tot4, 256), 256, 0, stream>>>(
            wsRaw, stMean, stIstd, br4, feat4, H4 * W4, 48, tot4);
    }
}

// Round 3
// 2901.602 us; speedup vs baseline: 7.8716x; 1.6480x over previous
//
#include <hip/hip_runtime.h>
#include <hip/hip_bf16.h>

typedef __attribute__((ext_vector_type(8))) short bf16x8;
typedef __attribute__((ext_vector_type(4))) float f32x4;

static inline int cdiv(int a, int b) { return (a + b - 1) / b; }

__device__ __forceinline__ ushort f2bf(float f) {
    unsigned u = __float_as_uint(f);
    unsigned r = (u + 0x7FFFu + ((u >> 16) & 1u)) >> 16;
    return (ushort)r;
}

// ---------------------------------------------------------------------------
// Weight repack: w[co][ci][t] (fp32) -> wt[t][co][ci_pad] (bf16), zero-pad ci.
// ---------------------------------------------------------------------------
__global__ __launch_bounds__(256)
void transpose_w(const float* __restrict__ w, ushort* __restrict__ wt,
                 int Cout, int Cin, int Cin_pad, int KK, int total) {
    int idx = blockIdx.x * 256 + threadIdx.x;
    if (idx >= total) return;
    int ci = idx % Cin_pad;
    int rem = idx / Cin_pad;
    int co = rem % Cout;
    int t  = rem / Cout;
    float v = (ci < Cin) ? w[((size_t)co * Cin + ci) * KK + t] : 0.f;
    wt[idx] = f2bf(v);
}

// ---------------------------------------------------------------------------
// Implicit-GEMM conv via MFMA 16x16x32 bf16.
//   M = Cout, N = B*H*W (2D spatial tiles TYxTX), K = Cin_pad*K*K (t-major).
// Block = 256 thr / 4 waves. NSPLIT waves split pixels, 4/NSPLIT split M.
// Per 32-ci chunk: stage halo tile [hy][hx][ci] in LDS (PITCH=40 bf16), then
// for each tap t read shifted B-frags from LDS; A-frags stream from global
// (pre-packed bf16, prefetched one tap ahead). acc in MFMA AGPRs, fp32 out.
// Main-conv bias omitted (InstanceNorm cancels it).
// ---------------------------------------------------------------------------
template<int K, int TY, int TX, int NSPLIT, int MT>
__global__ __launch_bounds__(256)
void conv_mfma(const float* __restrict__ in1, int C1,
               const float* __restrict__ in2, int C2, int Cin,
               const ushort* __restrict__ wt,
               float* __restrict__ outRaw,
               int H, int W, int Cout, int Cin_pad,
               int tilesX, int tilesY) {
    constexpr int P = K / 2;
    constexpr int HY = TY + K - 1, HX = TX + K - 1;
    constexpr int PITCH = 40;          // bf16 per (hy,hx) pos: 32 ci + pad, 16B-aligned
    constexpr int KK = K * K;
    constexpr int NPX = TY * TX;
    constexpr int PXW = NPX / NSPLIT;  // pixels per wave
    constexpr int NT = PXW / 16;       // n-tiles per wave
    constexpr int NPOS = HY * HX;
    constexpr int NITER = (NPOS * 16 + 255) / 256;

    __shared__ ushort sT[NPOS * PITCH];

    const int tid = threadIdx.x;
    const int lane = tid & 63, wv = tid >> 6;
    const int nwave = wv % NSPLIT, mwave = wv / NSPLIT;
    const int l15 = lane & 15, lg = lane >> 4;

    int tile = blockIdx.x;
    const int txi = tile % tilesX;
    int rem = tile / tilesX;
    const int tyi = rem % tilesY;
    const int b = rem / tilesY;
    const int x0 = txi * TX, y0 = tyi * TY;
    const size_t HW = (size_t)H * W;

    const int co0 = mwave * (MT * 16);

    int posBase[NT], py_[NT], px_[NT];
    #pragma unroll
    for (int nt = 0; nt < NT; ++nt) {
        int pidx = nwave * PXW + nt * 16 + l15;
        int py = pidx / TX, px = pidx % TX;
        py_[nt] = py; px_[nt] = px;
        posBase[nt] = (py * HX + px) * PITCH + lg * 8;
    }
    const int aoff = l15 * Cin_pad + lg * 8;

    f32x4 acc[MT][NT];
    #pragma unroll
    for (int i = 0; i < MT; ++i)
        #pragma unroll
        for (int j = 0; j < NT; ++j) acc[i][j] = (f32x4)0.f;

    const int nchunks = Cin_pad / 32;
    for (int c = 0; c < nchunks; ++c) {
        const int ci0 = c * 32;
        __syncthreads();
        // ---- stage halo tile (ci pairs packed to b32 writes) ----
        #pragma unroll
        for (int it = 0; it < NITER; ++it) {
            int idx = it * 256 + tid;
            if (idx < NPOS * 16) {
                int pos = idx % NPOS;
                int cp  = idx / NPOS;
                int hy = pos / HX, hx = pos % HX;
                int y = y0 - P + hy, x = x0 - P + hx;
                int ci = ci0 + cp * 2;
                unsigned pk = 0;
                if ((unsigned)y < (unsigned)H && (unsigned)x < (unsigned)W && ci < Cin) {
                    const float* src; int cbase;
                    if (ci < C1) { src = in1; cbase = b * C1 + ci; }
                    else         { src = in2; cbase = b * C2 + (ci - C1); }
                    const float* p0 = src + (size_t)cbase * HW + (size_t)y * W + x;
                    float v0 = p0[0];
                    float v1 = (ci + 1 < Cin) ? p0[HW] : 0.f;
                    pk = (unsigned)f2bf(v0) | ((unsigned)f2bf(v1) << 16);
                }
                *(unsigned*)&sT[pos * PITCH + cp * 2] = pk;
            }
        }
        __syncthreads();

        // ---- A prefetch for t=0 ----
        bf16x8 afA[MT];
        {
            const ushort* ap = wt + (size_t)co0 * Cin_pad + ci0 + aoff;
            #pragma unroll
            for (int mt = 0; mt < MT; ++mt)
                afA[mt] = *(const bf16x8*)(ap + (size_t)mt * 16 * Cin_pad);
        }
        #pragma unroll
        for (int t = 0; t < KK; ++t) {
            bf16x8 afB[MT];
            if (t + 1 < KK) {
                const ushort* ap = wt + (size_t)((t + 1) * Cout + co0) * Cin_pad + ci0 + aoff;
                #pragma unroll
                for (int mt = 0; mt < MT; ++mt)
                    afB[mt] = *(const bf16x8*)(ap + (size_t)mt * 16 * Cin_pad);
            }
            const int ky = t / K, kx = t % K;
            const int tOff = (ky * HX + kx) * PITCH;
            bf16x8 bf[NT];
            #pragma unroll
            for (int nt = 0; nt < NT; ++nt)
                bf[nt] = *(const bf16x8*)(sT + posBase[nt] + tOff);
            #pragma unroll
            for (int mt = 0; mt < MT; ++mt)
                #pragma unroll
                for (int nt = 0; nt < NT; ++nt)
                    acc[mt][nt] = __builtin_amdgcn_mfma_f32_16x16x32_bf16(
                        afA[mt], bf[nt], acc[mt][nt], 0, 0, 0);
            if (t + 1 < KK) {
                #pragma unroll
                for (int mt = 0; mt < MT; ++mt) afA[mt] = afB[mt];
            }
        }
    }

    // ---- store C (fp32 raw) ----
    #pragma unroll
    for (int mt = 0; mt < MT; ++mt) {
        #pragma unroll
        for (int nt = 0; nt < NT; ++nt) {
            int y = y0 + py_[nt], x = x0 + px_[nt];
            if (y < H && x < W) {
                #pragma unroll
                for (int r = 0; r < 4; ++r) {
                    int co = co0 + mt * 16 + lg * 4 + r;
                    outRaw[((size_t)(b * Cout + co)) * HW + (size_t)y * W + x] = acc[mt][nt][r];
                }
            }
        }
    }
}

// ---------------------------------------------------------------------------
// ConvTranspose2d k=3, stride=2, pad=1, output_pad=1, no bias (fp32 direct).
// ---------------------------------------------------------------------------
__global__ __launch_bounds__(256)
void convt2x_k3(const float* __restrict__ in,
                const float* __restrict__ wt,
                float* __restrict__ out,
                int Cin, int Cout, int Hin, int Win) {
    extern __shared__ float wlds[];  // Cin*9
    const int co = blockIdx.y, b = blockIdx.z;
    for (int i = threadIdx.x; i < Cin * 9; i += 256)
        wlds[i] = wt[(size_t)(i / 9) * Cout * 9 + (size_t)co * 9 + (i % 9)];
    __syncthreads();

    const int Ho = 2 * Hin, Wo = 2 * Win;
    const int HWo = Ho * Wo, HWi = Hin * Win;
    const float* inb = in + (size_t)b * Cin * HWi;
    float* ob = out + ((size_t)(b * Cout + co)) * HWo;

    #pragma unroll
    for (int k = 0; k < 4; ++k) {
        int px = blockIdx.x * 1024 + k * 256 + threadIdx.x;
        if (px >= HWo) continue;
        int ox = px % Wo, oy = px / Wo;
        int iys[2], kys[2], nky = 0;
        int ixs[2], kxs[2], nkx = 0;
        #pragma unroll
        for (int t = 0; t < 3; ++t) {
            int ty = oy + 1 - t;
            if (!(ty & 1)) { int iy = ty >> 1; if ((unsigned)iy < (unsigned)Hin) { iys[nky] = iy; kys[nky] = t; ++nky; } }
            int tx = ox + 1 - t;
            if (!(tx & 1)) { int ix = tx >> 1; if ((unsigned)ix < (unsigned)Win) { ixs[nkx] = ix; kxs[nkx] = t; ++nkx; } }
        }
        float acc = 0.f;
        for (int ci = 0; ci < Cin; ++ci) {
            const float* src = inb + (size_t)ci * HWi;
            const float* wc = &wlds[ci * 9];
            for (int a = 0; a < nky; ++a) {
                int rb = iys[a] * Win, wb = kys[a] * 3;
                for (int c2 = 0; c2 < nkx; ++c2)
                    acc = fmaf(src[rb + ixs[c2]], wc[wb + kxs[c2]], acc);
            }
        }
        ob[px] = acc;
    }
}

// ---------------------------------------------------------------------------
// InstanceNorm stats: one block per (b,c). Biased variance, eps=1e-5.
// ---------------------------------------------------------------------------
__global__ __launch_bounds__(256)
void inorm_stats(const float* __restrict__ x,
                 float* __restrict__ mean,
                 float* __restrict__ istd, int HW) {
    int bc = blockIdx.x;
    const float4* p = (const float4*)(x + (size_t)bc * HW);
    int n4 = HW >> 2;
    float s = 0.f, ss = 0.f;
    for (int i = threadIdx.x; i < n4; i += 256) {
        float4 v = p[i];
        s += v.x + v.y + v.z + v.w;
        ss += v.x * v.x + v.y * v.y + v.z * v.z + v.w * v.w;
    }
    #pragma unroll
    for (int o = 32; o > 0; o >>= 1) {
        s  += __shfl_down(s, o);
        ss += __shfl_down(ss, o);
    }
    __shared__ float sh[4][2];
    int wid = threadIdx.x >> 6, ln = threadIdx.x & 63;
    if (ln == 0) { sh[wid][0] = s; sh[wid][1] = ss; }
    __syncthreads();
    if (threadIdx.x == 0) {
        float S = 0.f, SS = 0.f;
        for (int i = 0; i < 4; ++i) { S += sh[i][0]; SS += sh[i][1]; }
        float m = S / HW;
        float v = SS / HW - m * m;
        v = v > 0.f ? v : 0.f;
        mean[bc] = m;
        istd[bc] = rsqrtf(v + 1e-5f);
    }
}

// ---------------------------------------------------------------------------
// Epilogue: feat = relu((raw - m)*istd) [+ res + br[co]]
// ---------------------------------------------------------------------------
template<bool HAS_RES>
__global__ __launch_bounds__(256)
void epilogue_k(const float* __restrict__ raw,
                const float* __restrict__ mean,
                const float* __restrict__ istd,
                const float* __restrict__ res,
                const float* __restrict__ br,
                float* __restrict__ feat,
                int HW, int Cout, int total4) {
    int i = blockIdx.x * 256 + threadIdx.x;
    if (i >= total4) return;
    int bc = (int)(((long long)i * 4) / HW);
    float m = mean[bc], is = istd[bc];
    float4 r = ((const float4*)raw)[i];
    float4 o;
    o.x = fmaxf((r.x - m) * is, 0.f);
    o.y = fmaxf((r.y - m) * is, 0.f);
    o.z = fmaxf((r.z - m) * is, 0.f);
    o.w = fmaxf((r.w - m) * is, 0.f);
    if (HAS_RES) {
        float bb = br[bc % Cout];
        float4 e = ((const float4*)res)[i];
        o.x += e.x + bb; o.y += e.y + bb; o.z += e.z + bb; o.w += e.w + bb;
    }
    ((float4*)feat)[i] = o;
}

extern "C" void kernel_launch(void* const* d_in, const int* in_sizes, int n_in,
                              void* d_out, int out_size, void* d_ws, size_t ws_size,
                              hipStream_t stream) {
    const float* f4   = (const float*)d_in[0];
    const float* f8   = (const float*)d_in[1];
    const float* f16  = (const float*)d_in[2];
    const float* f32  = (const float*)d_in[3];
    const float* w32  = (const float*)d_in[4];
    const float* wt32 = (const float*)d_in[6];
    const float* w16  = (const float*)d_in[7];
    const float* wr16 = (const float*)d_in[9];
    const float* br16 = (const float*)d_in[10];
    const float* wt16 = (const float*)d_in[11];
    const float* w8   = (const float*)d_in[12];
    const float* wr8  = (const float*)d_in[14];
    const float* br8  = (const float*)d_in[15];
    const float* wt8  = (const float*)d_in[16];
    const float* w4   = (const float*)d_in[17];
    const float* wr4  = (const float*)d_in[19];
    const float* br4  = (const float*)d_in[20];
    // main-conv biases cancel under InstanceNorm -> unused.

    float* out = (float*)d_out;

    const int B = 2, C = 256;
    const int H4 = 160, W4 = 240;
    const int H8 = 80,  W8 = 120;
    const int H16 = 40, W16 = 60;
    const int H32 = 20, W32 = 30;

    float* feat4  = out;
    float* feat8  = out + (size_t)B * 48 * H4 * W4;
    float* feat16 = feat8 + (size_t)B * 64 * H8 * W8;
    float* feat32 = feat16 + (size_t)B * 192 * H16 * W16;

    // ws: up-buffer | raw conv output | stats   (same 29.5MB footprint as R1)
    const size_t bufElems = (size_t)B * 48 * H4 * W4;  // 3,686,400
    float* wsUp   = (float*)d_ws;
    float* wsRaw  = wsUp + bufElems;
    float* stMean = wsRaw + bufElems;
    float* stIstd = stMean + 512;

    // bf16 repacked weights live in the feat4 output region (written last).
    // Segments (ushort units):
    ushort* wb = (ushort*)feat4;
    ushort* W32p = wb;                         // 9*160*256   = 368640
    ushort* W16p = W32p + 9 * 160 * 256;       // 25*192*448  = 2150400
    ushort* W8p  = W16p + 25 * 192 * 448;      // 25*64*320   = 512000
    ushort* W4p  = W8p  + 25 * 64 * 320;       // 25*48*320   = 384000
    ushort* R16p = W4p  + 25 * 48 * 320;       // 192*256     = 49152
    ushort* R8p  = R16p + 192 * 256;           // 64*256      = 16384
    ushort* R4p  = R8p  + 64 * 256;            // 48*256      = 12288

    // ---- weight repacks ----
    {
        int t1 = 9 * 160 * 256;
        transpose_w<<<cdiv(t1, 256), 256, 0, stream>>>(w32, W32p, 160, 256, 256, 9, t1);
        int t2 = 25 * 192 * 448;
        transpose_w<<<cdiv(t2, 256), 256, 0, stream>>>(w16, W16p, 192, 448, 448, 25, t2);
        int t3 = 25 * 64 * 320;
        transpose_w<<<cdiv(t3, 256), 256, 0, stream>>>(w8, W8p, 64, 320, 320, 25, t3);
        int t4 = 25 * 48 * 320;
        transpose_w<<<cdiv(t4, 256), 256, 0, stream>>>(w4, W4p, 48, 304, 320, 25, t4);
        int t5 = 192 * 256;
        transpose_w<<<cdiv(t5, 256), 256, 0, stream>>>(wr16, R16p, 192, 256, 256, 1, t5);
        int t6 = 64 * 256;
        transpose_w<<<cdiv(t6, 256), 256, 0, stream>>>(wr8, R8p, 64, 256, 256, 1, t6);
        int t7 = 48 * 256;
        transpose_w<<<cdiv(t7, 256), 256, 0, stream>>>(wr4, R4p, 48, 256, 256, 1, t7);
    }

    // ---------------- stage 32 (K=3, Cin=256, Cout=160, 20x30) ----------------
    {
        int tX = cdiv(W32, 16), tY = cdiv(H32, 8);
        conv_mfma<3, 8, 16, 2, 5><<<tX * tY * B, 256, 0, stream>>>(
            f32, C, nullptr, 0, C, W32p, wsRaw, H32, W32, 160, 256, tX, tY);
        inorm_stats<<<B * 160, 256, 0, stream>>>(wsRaw, stMean, stIstd, H32 * W32);
        int tot4 = B * 160 * H32 * W32 / 4;
        epilogue_k<false><<<cdiv(tot4, 256), 256, 0, stream>>>(
            wsRaw, stMean, stIstd, nullptr, nullptr, feat32, H32 * W32, 160, tot4);
        int HWo = (2 * H32) * (2 * W32);
        dim3 gu(cdiv(HWo, 1024), 192, B);
        convt2x_k3<<<gu, 256, 160 * 9 * 4, stream>>>(feat32, wt32, wsUp, 160, 192, H32, W32);
    }
    // ---------------- stage 16 (K=5, Cin=256+192, Cout=192, 40x60) ------------
    {
        int tX = cdiv(W16, 8), tY = cdiv(H16, 8);
        conv_mfma<5, 8, 8, 1, 3><<<tX * tY * B, 256, 0, stream>>>(
            f16, C, wsUp, 192, 448, W16p, wsRaw, H16, W16, 192, 448, tX, tY);
        conv_mfma<1, 8, 8, 1, 3><<<tX * tY * B, 256, 0, stream>>>(
            f16, C, nullptr, 0, C, R16p, feat16, H16, W16, 192, 256, tX, tY);
        inorm_stats<<<B * 192, 256, 0, stream>>>(wsRaw, stMean, stIstd, H16 * W16);
        int tot4 = B * 192 * H16 * W16 / 4;
        epilogue_k<true><<<cdiv(tot4, 256), 256, 0, stream>>>(
            wsRaw, stMean, stIstd, feat16, br16, feat16, H16 * W16, 192, tot4);
        int HWo = (2 * H16) * (2 * W16);
        dim3 gu(cdiv(HWo, 1024), 64, B);
        convt2x_k3<<<gu, 256, 192 * 9 * 4, stream>>>(feat16, wt16, wsUp, 192, 64, H16, W16);
    }
    // ---------------- stage 8 (K=5, Cin=256+64, Cout=64, 80x120) --------------
    {
        int tX = cdiv(W8, 16), tY = cdiv(H8, 8);
        conv_mfma<5, 8, 16, 2, 2><<<tX * tY * B, 256, 0, stream>>>(
            f8, C, wsUp, 64, 320, W8p, wsRaw, H8, W8, 64, 320, tX, tY);
        conv_mfma<1, 8, 16, 2, 2><<<tX * tY * B, 256, 0, stream>>>(
            f8, C, nullptr, 0, C, R8p, feat8, H8, W8, 64, 256, tX, tY);
        inorm_stats<<<B * 64, 256, 0, stream>>>(wsRaw, stMean, stIstd, H8 * W8);
        int tot4 = B * 64 * H8 * W8 / 4;
        epilogue_k<true><<<cdiv(tot4, 256), 256, 0, stream>>>(
            wsRaw, stMean, stIstd, feat8, br8, feat8, H8 * W8, 64, tot4);
        int HWo = (2 * H8) * (2 * W8);
        dim3 gu(cdiv(HWo, 1024), 48, B);
        convt2x_k3<<<gu, 256, 64 * 9 * 4, stream>>>(feat8, wt8, wsUp, 64, 48, H8, W8);
    }
    // ---------------- stage 4 (K=5, Cin=256+48, Cout=48, 160x240) -------------
    {
        int tX = cdiv(W4, 16), tY = cdiv(H4, 16);
        conv_mfma<5, 16, 16, 4, 3><<<tX * tY * B, 256, 0, stream>>>(
            f4, C, wsUp, 48, 304, W4p, wsRaw, H4, W4, 48, 320, tX, tY);
        // residual -> wsUp (free after conv4 consumed it); feat4 region still holds W''.
        conv_mfma<1, 16, 16, 4, 3><<<tX * tY * B, 256, 0, stream>>>(
            f4, C, nullptr, 0, C, R4p, wsUp, H4, W4, 48, 256, tX, tY);
        inorm_stats<<<B * 48, 256, 0, stream>>>(wsRaw, stMean, stIstd, H4 * W4);
        int tot4 = B * 48 * H4 * W4 / 4;
        epilogue_k<true><<<cdiv(tot4, 256), 256, 0, stream>>>(
            wsRaw, stMean, stIstd, wsUp, br4, feat4, H4 * W4, 48, tot4);
    }
}

// Round 4
// 1400.100 us; speedup vs baseline: 16.3133x; 2.0724x over previous
//
#include <hip/hip_runtime.h>
#include <hip/hip_bf16.h>

typedef __attribute__((ext_vector_type(8))) short bf16x8;
typedef __attribute__((ext_vector_type(4))) float f32x4;

static inline int cdiv(int a, int b) { return (a + b - 1) / b; }

__device__ __forceinline__ ushort f2bf(float f) {
    unsigned u = __float_as_uint(f);
    unsigned r = (u + 0x7FFFu + ((u >> 16) & 1u)) >> 16;
    return (ushort)r;
}

// ---------------------------------------------------------------------------
// Weight repack: w[co][ci][t] (fp32) -> wt[t][co][ci_pad] (bf16), zero-pad ci.
// ---------------------------------------------------------------------------
__global__ __launch_bounds__(256)
void transpose_w(const float* __restrict__ w, ushort* __restrict__ wt,
                 int Cout, int Cin, int Cin_pad, int KK, int total) {
    int idx = blockIdx.x * 256 + threadIdx.x;
    if (idx >= total) return;
    int ci = idx % Cin_pad;
    int rem = idx / Cin_pad;
    int co = rem % Cout;
    int t  = rem / Cout;
    float v = (ci < Cin) ? w[((size_t)co * Cin + ci) * KK + t] : 0.f;
    wt[idx] = f2bf(v);
}

// ---------------------------------------------------------------------------
// ConvTranspose weight repack: torch wt[ci][co][ky][kx] -> wtp[t][co][ci_pad]
// t = phase-major tap index (see convt_mfma tap tables).
// ---------------------------------------------------------------------------
__device__ const int g_tky[9] = {1, 1, 1, 0, 2, 0, 0, 2, 2};
__device__ const int g_tkx[9] = {1, 0, 2, 1, 1, 0, 2, 0, 2};

__global__ __launch_bounds__(256)
void transpose_wt(const float* __restrict__ wt, ushort* __restrict__ dst,
                  int Cin, int Cout, int Cin_pad, int total) {
    int idx = blockIdx.x * 256 + threadIdx.x;
    if (idx >= total) return;
    int ci = idx % Cin_pad;
    int rem = idx / Cin_pad;
    int co = rem % Cout;
    int t  = rem / Cout;
    float v = 0.f;
    if (ci < Cin)
        v = wt[((size_t)(ci * Cout + co) * 3 + g_tky[t]) * 3 + g_tkx[t]];
    dst[idx] = f2bf(v);
}

// ---------------------------------------------------------------------------
// Implicit-GEMM conv via MFMA 16x16x32 bf16.
//   M = Cout, N = B*H*W (2D spatial tiles TYxTX), K = Cin_pad*K*K (t-major).
// Block = 256 thr / 4 waves. NSPLIT waves split pixels, 4/NSPLIT split M.
// Per 32-ci chunk: stage halo tile [hy][hx][ci] in LDS (PITCH=40 bf16), then
// for each tap t read shifted B-frags from LDS; A-frags stream from global
// (pre-packed bf16, prefetched one tap ahead). Main-conv bias omitted
// (InstanceNorm cancels it).
// ---------------------------------------------------------------------------
template<int K, int TY, int TX, int NSPLIT, int MT>
__global__ __launch_bounds__(256)
void conv_mfma(const float* __restrict__ in1, int C1,
               const float* __restrict__ in2, int C2, int Cin,
               const ushort* __restrict__ wt,
               float* __restrict__ outRaw,
               int H, int W, int Cout, int Cin_pad,
               int tilesX, int tilesY) {
    constexpr int P = K / 2;
    constexpr int HY = TY + K - 1, HX = TX + K - 1;
    constexpr int PITCH = 40;
    constexpr int KK = K * K;
    constexpr int NPX = TY * TX;
    constexpr int PXW = NPX / NSPLIT;
    constexpr int NT = PXW / 16;
    constexpr int NPOS = HY * HX;
    constexpr int NITER = (NPOS * 16 + 255) / 256;

    __shared__ ushort sT[NPOS * PITCH];

    const int tid = threadIdx.x;
    const int lane = tid & 63, wv = tid >> 6;
    const int nwave = wv % NSPLIT, mwave = wv / NSPLIT;
    const int l15 = lane & 15, lg = lane >> 4;

    int tile = blockIdx.x;
    const int txi = tile % tilesX;
    int rem = tile / tilesX;
    const int tyi = rem % tilesY;
    const int b = rem / tilesY;
    const int x0 = txi * TX, y0 = tyi * TY;
    const size_t HW = (size_t)H * W;

    const int co0 = mwave * (MT * 16);

    int posBase[NT], py_[NT], px_[NT];
    #pragma unroll
    for (int nt = 0; nt < NT; ++nt) {
        int pidx = nwave * PXW + nt * 16 + l15;
        int py = pidx / TX, px = pidx % TX;
        py_[nt] = py; px_[nt] = px;
        posBase[nt] = (py * HX + px) * PITCH + lg * 8;
    }
    const int aoff = l15 * Cin_pad + lg * 8;

    f32x4 acc[MT][NT];
    #pragma unroll
    for (int i = 0; i < MT; ++i)
        #pragma unroll
        for (int j = 0; j < NT; ++j) acc[i][j] = (f32x4)0.f;

    const int nchunks = Cin_pad / 32;
    for (int c = 0; c < nchunks; ++c) {
        const int ci0 = c * 32;
        __syncthreads();
        #pragma unroll
        for (int it = 0; it < NITER; ++it) {
            int idx = it * 256 + tid;
            if (idx < NPOS * 16) {
                int pos = idx % NPOS;
                int cp  = idx / NPOS;
                int hy = pos / HX, hx = pos % HX;
                int y = y0 - P + hy, x = x0 - P + hx;
                int ci = ci0 + cp * 2;
                unsigned pk = 0;
                if ((unsigned)y < (unsigned)H && (unsigned)x < (unsigned)W && ci < Cin) {
                    const float* src; int cbase;
                    if (ci < C1) { src = in1; cbase = b * C1 + ci; }
                    else         { src = in2; cbase = b * C2 + (ci - C1); }
                    const float* p0 = src + (size_t)cbase * HW + (size_t)y * W + x;
                    float v0 = p0[0];
                    float v1 = (ci + 1 < Cin) ? p0[HW] : 0.f;
                    pk = (unsigned)f2bf(v0) | ((unsigned)f2bf(v1) << 16);
                }
                *(unsigned*)&sT[pos * PITCH + cp * 2] = pk;
            }
        }
        __syncthreads();

        bf16x8 afA[MT];
        {
            const ushort* ap = wt + (size_t)co0 * Cin_pad + ci0 + aoff;
            #pragma unroll
            for (int mt = 0; mt < MT; ++mt)
                afA[mt] = *(const bf16x8*)(ap + (size_t)mt * 16 * Cin_pad);
        }
        #pragma unroll
        for (int t = 0; t < KK; ++t) {
            bf16x8 afB[MT];
            if (t + 1 < KK) {
                const ushort* ap = wt + (size_t)((t + 1) * Cout + co0) * Cin_pad + ci0 + aoff;
                #pragma unroll
                for (int mt = 0; mt < MT; ++mt)
                    afB[mt] = *(const bf16x8*)(ap + (size_t)mt * 16 * Cin_pad);
            }
            const int ky = t / K, kx = t % K;
            const int tOff = (ky * HX + kx) * PITCH;
            bf16x8 bf[NT];
            #pragma unroll
            for (int nt = 0; nt < NT; ++nt)
                bf[nt] = *(const bf16x8*)(sT + posBase[nt] + tOff);
            #pragma unroll
            for (int mt = 0; mt < MT; ++mt)
                #pragma unroll
                for (int nt = 0; nt < NT; ++nt)
                    acc[mt][nt] = __builtin_amdgcn_mfma_f32_16x16x32_bf16(
                        afA[mt], bf[nt], acc[mt][nt], 0, 0, 0);
            if (t + 1 < KK) {
                #pragma unroll
                for (int mt = 0; mt < MT; ++mt) afA[mt] = afB[mt];
            }
        }
    }

    #pragma unroll
    for (int mt = 0; mt < MT; ++mt) {
        #pragma unroll
        for (int nt = 0; nt < NT; ++nt) {
            int y = y0 + py_[nt], x = x0 + px_[nt];
            if (y < H && x < W) {
                #pragma unroll
                for (int r = 0; r < 4; ++r) {
                    int co = co0 + mt * 16 + lg * 4 + r;
                    outRaw[((size_t)(b * Cout + co)) * HW + (size_t)y * W + x] = acc[mt][nt][r];
                }
            }
        }
    }
}

// ---------------------------------------------------------------------------
// ConvTranspose2d k3/s2/p1/op1 via MFMA, 4-phase subpixel decomposition.
// Phase p=(dy,dx): out(2y+dy, 2x+dx) needs only in(y+{0,1}, x+{0,1}).
// Tap order t=0..8 (phase-major):
//   t:     0 | 1  2 | 3  4 | 5  6  7  8
//   phase: 0 | 1  1 | 2  2 | 3  3  3  3
//   oy:    0 | 0  0 | 1  0 | 1  1  0  0
//   ox:    0 | 1  0 | 0  0 | 1  0  1  0
// (matching ky/kx in g_tky/g_tkx for the weight repack).
// N-tile = TY x TX input pixels; each produces a 2x2 output quad.
// ---------------------------------------------------------------------------
template<int TY, int TX, int NSPLIT, int MT>
__global__ __launch_bounds__(256)
void convt_mfma(const float* __restrict__ in,
                const ushort* __restrict__ wtp,
                float* __restrict__ out,
                int Cin, int Cout, int Cin_pad, int Hin, int Win,
                int tilesX, int tilesY) {
    constexpr int HY = TY + 1, HX = TX + 1;
    constexpr int PITCH = 40;
    constexpr int NPX = TY * TX;
    constexpr int PXW = NPX / NSPLIT;
    constexpr int NT = PXW / 16;
    constexpr int NPOS = HY * HX;
    constexpr int NITER = (NPOS * 16 + 255) / 256;

    __shared__ ushort sT[NPOS * PITCH];

    constexpr int toy[9] = {0, 0, 0, 1, 0, 1, 1, 0, 0};
    constexpr int tox[9] = {0, 1, 0, 0, 0, 1, 0, 1, 0};
    constexpr int tph[9] = {0, 1, 1, 2, 2, 3, 3, 3, 3};

    const int tid = threadIdx.x;
    const int lane = tid & 63, wv = tid >> 6;
    const int nwave = wv % NSPLIT, mwave = wv / NSPLIT;
    const int l15 = lane & 15, lg = lane >> 4;

    int tile = blockIdx.x;
    const int txi = tile % tilesX;
    int rem = tile / tilesX;
    const int tyi = rem % tilesY;
    const int b = rem / tilesY;
    const int x0 = txi * TX, y0 = tyi * TY;
    const size_t HWi = (size_t)Hin * Win;
    const int Wo = 2 * Win;
    const size_t HWo = (size_t)4 * HWi;

    const int co0 = mwave * (MT * 16);

    int posBase[NT], py_[NT], px_[NT];
    #pragma unroll
    for (int nt = 0; nt < NT; ++nt) {
        int pidx = nwave * PXW + nt * 16 + l15;
        int py = pidx / TX, px = pidx % TX;
        py_[nt] = py; px_[nt] = px;
        posBase[nt] = (py * HX + px) * PITCH + lg * 8;
    }
    const int aoff = l15 * Cin_pad + lg * 8;

    f32x4 acc[4][MT][NT];
    #pragma unroll
    for (int p = 0; p < 4; ++p)
        #pragma unroll
        for (int i = 0; i < MT; ++i)
            #pragma unroll
            for (int j = 0; j < NT; ++j) acc[p][i][j] = (f32x4)0.f;

    const int nchunks = Cin_pad / 32;
    for (int c = 0; c < nchunks; ++c) {
        const int ci0 = c * 32;
        __syncthreads();
        #pragma unroll
        for (int it = 0; it < NITER; ++it) {
            int idx = it * 256 + tid;
            if (idx < NPOS * 16) {
                int pos = idx % NPOS;
                int cp  = idx / NPOS;
                int hy = pos / HX, hx = pos % HX;
                int y = y0 + hy, x = x0 + hx;   // +1 halo only (no -P)
                int ci = ci0 + cp * 2;
                unsigned pk = 0;
                if ((unsigned)y < (unsigned)Hin && (unsigned)x < (unsigned)Win && ci < Cin) {
                    const float* p0 = in + (size_t)(b * Cin + ci) * HWi + (size_t)y * Win + x;
                    float v0 = p0[0];
                    float v1 = (ci + 1 < Cin) ? p0[HWi] : 0.f;
                    pk = (unsigned)f2bf(v0) | ((unsigned)f2bf(v1) << 16);
                }
                *(unsigned*)&sT[pos * PITCH + cp * 2] = pk;
            }
        }
        __syncthreads();

        bf16x8 afA[MT];
        {
            const ushort* ap = wtp + (size_t)co0 * Cin_pad + ci0 + aoff;
            #pragma unroll
            for (int mt = 0; mt < MT; ++mt)
                afA[mt] = *(const bf16x8*)(ap + (size_t)mt * 16 * Cin_pad);
        }
        #pragma unroll
        for (int t = 0; t < 9; ++t) {
            bf16x8 afB[MT];
            if (t + 1 < 9) {
                const ushort* ap = wtp + (size_t)((t + 1) * Cout + co0) * Cin_pad + ci0 + aoff;
                #pragma unroll
                for (int mt = 0; mt < MT; ++mt)
                    afB[mt] = *(const bf16x8*)(ap + (size_t)mt * 16 * Cin_pad);
            }
            const int tOff = (toy[t] * HX + tox[t]) * PITCH;
            bf16x8 bf[NT];
            #pragma unroll
            for (int nt = 0; nt < NT; ++nt)
                bf[nt] = *(const bf16x8*)(sT + posBase[nt] + tOff);
            #pragma unroll
            for (int mt = 0; mt < MT; ++mt)
                #pragma unroll
                for (int nt = 0; nt < NT; ++nt)
                    acc[tph[t]][mt][nt] = __builtin_amdgcn_mfma_f32_16x16x32_bf16(
                        afA[mt], bf[nt], acc[tph[t]][mt][nt], 0, 0, 0);
            if (t + 1 < 9) {
                #pragma unroll
                for (int mt = 0; mt < MT; ++mt) afA[mt] = afB[mt];
            }
        }
    }

    #pragma unroll
    for (int p = 0; p < 4; ++p) {
        const int dy = p >> 1, dx = p & 1;
        #pragma unroll
        for (int mt = 0; mt < MT; ++mt) {
            #pragma unroll
            for (int nt = 0; nt < NT; ++nt) {
                int y = y0 + py_[nt], x = x0 + px_[nt];
                if (y < Hin && x < Win) {
                    #pragma unroll
                    for (int r = 0; r < 4; ++r) {
                        int co = co0 + mt * 16 + lg * 4 + r;
                        out[((size_t)(b * Cout + co)) * HWo + (size_t)(2 * y + dy) * Wo + (2 * x + dx)] =
                            acc[p][mt][nt][r];
                    }
                }
            }
        }
    }
}

// ---------------------------------------------------------------------------
// InstanceNorm stats: one block per (b,c). Biased variance, eps=1e-5.
// ---------------------------------------------------------------------------
__global__ __launch_bounds__(256)
void inorm_stats(const float* __restrict__ x,
                 float* __restrict__ mean,
                 float* __restrict__ istd, int HW) {
    int bc = blockIdx.x;
    const float4* p = (const float4*)(x + (size_t)bc * HW);
    int n4 = HW >> 2;
    float s = 0.f, ss = 0.f;
    for (int i = threadIdx.x; i < n4; i += 256) {
        float4 v = p[i];
        s += v.x + v.y + v.z + v.w;
        ss += v.x * v.x + v.y * v.y + v.z * v.z + v.w * v.w;
    }
    #pragma unroll
    for (int o = 32; o > 0; o >>= 1) {
        s  += __shfl_down(s, o);
        ss += __shfl_down(ss, o);
    }
    __shared__ float sh[4][2];
    int wid = threadIdx.x >> 6, ln = threadIdx.x & 63;
    if (ln == 0) { sh[wid][0] = s; sh[wid][1] = ss; }
    __syncthreads();
    if (threadIdx.x == 0) {
        float S = 0.f, SS = 0.f;
        for (int i = 0; i < 4; ++i) { S += sh[i][0]; SS += sh[i][1]; }
        float m = S / HW;
        float v = SS / HW - m * m;
        v = v > 0.f ? v : 0.f;
        mean[bc] = m;
        istd[bc] = rsqrtf(v + 1e-5f);
    }
}

// ---------------------------------------------------------------------------
// Epilogue: feat = relu((raw - m)*istd) [+ res + br[co]]
// ---------------------------------------------------------------------------
template<bool HAS_RES>
__global__ __launch_bounds__(256)
void epilogue_k(const float* __restrict__ raw,
                const float* __restrict__ mean,
                const float* __restrict__ istd,
                const float* __restrict__ res,
                const float* __restrict__ br,
                float* __restrict__ feat,
                int HW, int Cout, int total4) {
    int i = blockIdx.x * 256 + threadIdx.x;
    if (i >= total4) return;
    int bc = (int)(((long long)i * 4) / HW);
    float m = mean[bc], is = istd[bc];
    float4 r = ((const float4*)raw)[i];
    float4 o;
    o.x = fmaxf((r.x - m) * is, 0.f);
    o.y = fmaxf((r.y - m) * is, 0.f);
    o.z = fmaxf((r.z - m) * is, 0.f);
    o.w = fmaxf((r.w - m) * is, 0.f);
    if (HAS_RES) {
        float bb = br[bc % Cout];
        float4 e = ((const float4*)res)[i];
        o.x += e.x + bb; o.y += e.y + bb; o.z += e.z + bb; o.w += e.w + bb;
    }
    ((float4*)feat)[i] = o;
}

extern "C" void kernel_launch(void* const* d_in, const int* in_sizes, int n_in,
                              void* d_out, int out_size, void* d_ws, size_t ws_size,
                              hipStream_t stream) {
    const float* f4   = (const float*)d_in[0];
    const float* f8   = (const float*)d_in[1];
    const float* f16  = (const float*)d_in[2];
    const float* f32  = (const float*)d_in[3];
    const float* w32  = (const float*)d_in[4];
    const float* wt32 = (const float*)d_in[6];
    const float* w16  = (const float*)d_in[7];
    const float* wr16 = (const float*)d_in[9];
    const float* br16 = (const float*)d_in[10];
    const float* wt16 = (const float*)d_in[11];
    const float* w8   = (const float*)d_in[12];
    const float* wr8  = (const float*)d_in[14];
    const float* br8  = (const float*)d_in[15];
    const float* wt8  = (const float*)d_in[16];
    const float* w4   = (const float*)d_in[17];
    const float* wr4  = (const float*)d_in[19];
    const float* br4  = (const float*)d_in[20];
    // main-conv biases cancel under InstanceNorm -> unused.

    float* out = (float*)d_out;

    const int B = 2, C = 256;
    const int H4 = 160, W4 = 240;
    const int H8 = 80,  W8 = 120;
    const int H16 = 40, W16 = 60;
    const int H32 = 20, W32 = 30;

    float* feat4  = out;
    float* feat8  = out + (size_t)B * 48 * H4 * W4;
    float* feat16 = feat8 + (size_t)B * 64 * H8 * W8;
    float* feat32 = feat16 + (size_t)B * 192 * H16 * W16;

    const size_t bufElems = (size_t)B * 48 * H4 * W4;  // 3,686,400
    float* wsUp   = (float*)d_ws;
    float* wsRaw  = wsUp + bufElems;
    float* stMean = wsRaw + bufElems;
    float* stIstd = stMean + 512;

    // bf16 repacked weights live in the feat4 output region (written last).
    ushort* wb = (ushort*)feat4;
    ushort* W32p = wb;                          // 9*160*256
    ushort* W16p = W32p + 9 * 160 * 256;        // 25*192*448
    ushort* W8p  = W16p + 25 * 192 * 448;       // 25*64*320
    ushort* W4p  = W8p  + 25 * 64 * 320;        // 25*48*320
    ushort* R16p = W4p  + 25 * 48 * 320;        // 192*256
    ushort* R8p  = R16p + 192 * 256;            // 64*256
    ushort* R4p  = R8p  + 64 * 256;             // 48*256
    ushort* T32p = R4p  + 48 * 256;             // 9*192*160
    ushort* T16p = T32p + 9 * 192 * 160;        // 9*64*192
    ushort* T8p  = T16p + 9 * 64 * 192;         // 9*48*64
    // total ~3.9M ushorts = 7.8MB < feat4's 14.7MB.

    // ---- weight repacks ----
    {
        int t1 = 9 * 160 * 256;
        transpose_w<<<cdiv(t1, 256), 256, 0, stream>>>(w32, W32p, 160, 256, 256, 9, t1);
        int t2 = 25 * 192 * 448;
        transpose_w<<<cdiv(t2, 256), 256, 0, stream>>>(w16, W16p, 192, 448, 448, 25, t2);
        int t3 = 25 * 64 * 320;
        transpose_w<<<cdiv(t3, 256), 256, 0, stream>>>(w8, W8p, 64, 320, 320, 25, t3);
        int t4 = 25 * 48 * 320;
        transpose_w<<<cdiv(t4, 256), 256, 0, stream>>>(w4, W4p, 48, 304, 320, 25, t4);
        int t5 = 192 * 256;
        transpose_w<<<cdiv(t5, 256), 256, 0, stream>>>(wr16, R16p, 192, 256, 256, 1, t5);
        int t6 = 64 * 256;
        transpose_w<<<cdiv(t6, 256), 256, 0, stream>>>(wr8, R8p, 64, 256, 256, 1, t6);
        int t7 = 48 * 256;
        transpose_w<<<cdiv(t7, 256), 256, 0, stream>>>(wr4, R4p, 48, 256, 256, 1, t7);
        int u1 = 9 * 192 * 160;
        transpose_wt<<<cdiv(u1, 256), 256, 0, stream>>>(wt32, T32p, 160, 192, 160, u1);
        int u2 = 9 * 64 * 192;
        transpose_wt<<<cdiv(u2, 256), 256, 0, stream>>>(wt16, T16p, 192, 64, 192, u2);
        int u3 = 9 * 48 * 64;
        transpose_wt<<<cdiv(u3, 256), 256, 0, stream>>>(wt8, T8p, 64, 48, 64, u3);
    }

    // ---------------- stage 32 (K=3, Cin=256, Cout=160, 20x30) ----------------
    {
        int tX = cdiv(W32, 16), tY = cdiv(H32, 8);
        conv_mfma<3, 8, 16, 2, 5><<<tX * tY * B, 256, 0, stream>>>(
            f32, C, nullptr, 0, C, W32p, wsRaw, H32, W32, 160, 256, tX, tY);
        inorm_stats<<<B * 160, 256, 0, stream>>>(wsRaw, stMean, stIstd, H32 * W32);
        int tot4 = B * 160 * H32 * W32 / 4;
        epilogue_k<false><<<cdiv(tot4, 256), 256, 0, stream>>>(
            wsRaw, stMean, stIstd, nullptr, nullptr, feat32, H32 * W32, 160, tot4);
        // convT 160->192, 20x30 -> 40x60 : NSPLIT=1 (4 m-groups x MT=3 = 192)
        int uX = cdiv(W32, 8), uY = cdiv(H32, 2);
        convt_mfma<2, 8, 1, 3><<<uX * uY * B, 256, 0, stream>>>(
            feat32, T32p, wsUp, 160, 192, 160, H32, W32, uX, uY);
    }
    // ---------------- stage 16 (K=5, Cin=256+192, Cout=192, 40x60) ------------
    {
        int tX = cdiv(W16, 8), tY = cdiv(H16, 8);
        conv_mfma<5, 8, 8, 1, 3><<<tX * tY * B, 256, 0, stream>>>(
            f16, C, wsUp, 192, 448, W16p, wsRaw, H16, W16, 192, 448, tX, tY);
        conv_mfma<1, 8, 8, 1, 3><<<tX * tY * B, 256, 0, stream>>>(
            f16, C, nullptr, 0, C, R16p, feat16, H16, W16, 192, 256, tX, tY);
        inorm_stats<<<B * 192, 256, 0, stream>>>(wsRaw, stMean, stIstd, H16 * W16);
        int tot4 = B * 192 * H16 * W16 / 4;
        epilogue_k<true><<<cdiv(tot4, 256), 256, 0, stream>>>(
            wsRaw, stMean, stIstd, feat16, br16, feat16, H16 * W16, 192, tot4);
        // convT 192->64, 40x60 -> 80x120 : NSPLIT=2 (2 m-groups x MT=2 = 64)
        int uX = cdiv(W16, 8), uY = cdiv(H16, 4);
        convt_mfma<4, 8, 2, 2><<<uX * uY * B, 256, 0, stream>>>(
            feat16, T16p, wsUp, 192, 64, 192, H16, W16, uX, uY);
    }
    // ---------------- stage 8 (K=5, Cin=256+64, Cout=64, 80x120) --------------
    {
        int tX = cdiv(W8, 16), tY = cdiv(H8, 8);
        conv_mfma<5, 8, 16, 2, 2><<<tX * tY * B, 256, 0, stream>>>(
            f8, C, wsUp, 64, 320, W8p, wsRaw, H8, W8, 64, 320, tX, tY);
        conv_mfma<1, 8, 16, 2, 2><<<tX * tY * B, 256, 0, stream>>>(
            f8, C, nullptr, 0, C, R8p, feat8, H8, W8, 64, 256, tX, tY);
        inorm_stats<<<B * 64, 256, 0, stream>>>(wsRaw, stMean, stIstd, H8 * W8);
        int tot4 = B * 64 * H8 * W8 / 4;
        epilogue_k<true><<<cdiv(tot4, 256), 256, 0, stream>>>(
            wsRaw, stMean, stIstd, feat8, br8, feat8, H8 * W8, 64, tot4);
        // convT 64->48, 80x120 -> 160x240 : NSPLIT=4 (MT=3 -> 48)
        int uX = cdiv(W8, 16), uY = cdiv(H8, 4);
        convt_mfma<4, 16, 4, 3><<<uX * uY * B, 256, 0, stream>>>(
            feat8, T8p, wsUp, 64, 48, 64, H8, W8, uX, uY);
    }
    // ---------------- stage 4 (K=5, Cin=256+48, Cout=48, 160x240) -------------
    {
        int tX = cdiv(W4, 16), tY = cdiv(H4, 16);
        conv_mfma<5, 16, 16, 4, 3><<<tX * tY * B, 256, 0, stream>>>(
            f4, C, wsUp, 48, 304, W4p, wsRaw, H4, W4, 48, 320, tX, tY);
        conv_mfma<1, 16, 16, 4, 3><<<tX * tY * B, 256, 0, stream>>>(
            f4, C, nullptr, 0, C, R4p, wsUp, H4, W4, 48, 256, tX, tY);
        inorm_stats<<<B * 48, 256, 0, stream>>>(wsRaw, stMean, stIstd, H4 * W4);
        int tot4 = B * 48 * H4 * W4 / 4;
        epilogue_k<true><<<cdiv(tot4, 256), 256, 0, stream>>>(
            wsRaw, stMean, stIstd, wsUp, br4, feat4, H4 * W4, 48, tot4);
    }
}

// Round 5
// 777.484 us; speedup vs baseline: 29.3771x; 1.8008x over previous
//
#include <hip/hip_runtime.h>
#include <hip/hip_bf16.h>

typedef __attribute__((ext_vector_type(8))) short bf16x8;
typedef __attribute__((ext_vector_type(4))) float f32x4;

static inline int cdiv(int a, int b) { return (a + b - 1) / b; }

__device__ __forceinline__ ushort f2bf(float f) {
    unsigned u = __float_as_uint(f);
    unsigned r = (u + 0x7FFFu + ((u >> 16) & 1u)) >> 16;
    return (ushort)r;
}

// ---------------------------------------------------------------------------
// Weight repack: w[co][ci][t] (fp32) -> wt[t][co_pad][ci_pad] (bf16), zero-pad.
// ---------------------------------------------------------------------------
__global__ __launch_bounds__(256)
void transpose_w(const float* __restrict__ w, ushort* __restrict__ wt,
                 int Cout, int CoutPad, int Cin, int Cin_pad, int KK, int total) {
    int idx = blockIdx.x * 256 + threadIdx.x;
    if (idx >= total) return;
    int ci = idx % Cin_pad;
    int rem = idx / Cin_pad;
    int co = rem % CoutPad;
    int t  = rem / CoutPad;
    float v = (ci < Cin && co < Cout) ? w[((size_t)co * Cin + ci) * KK + t] : 0.f;
    wt[idx] = f2bf(v);
}

// ---------------------------------------------------------------------------
// ConvTranspose weight repack: torch wt[ci][co][ky][kx] -> wtp[t][co][ci_pad]
// ---------------------------------------------------------------------------
__device__ const int g_tky[9] = {1, 1, 1, 0, 2, 0, 0, 2, 2};
__device__ const int g_tkx[9] = {1, 0, 2, 1, 1, 0, 2, 0, 2};

__global__ __launch_bounds__(256)
void transpose_wt(const float* __restrict__ wt, ushort* __restrict__ dst,
                  int Cin, int Cout, int Cin_pad, int total) {
    int idx = blockIdx.x * 256 + threadIdx.x;
    if (idx >= total) return;
    int ci = idx % Cin_pad;
    int rem = idx / Cin_pad;
    int co = rem % Cout;
    int t  = rem / Cout;
    float v = 0.f;
    if (ci < Cin)
        v = wt[((size_t)(ci * Cout + co) * 3 + g_tky[t]) * 3 + g_tkx[t]];
    dst[idx] = f2bf(v);
}

// ---------------------------------------------------------------------------
// Implicit-GEMM conv via MFMA 16x16x32 bf16, v2.
//  - aligned halo staging (cols from x0-XOFF, XOFF=4) -> float4 fast path
//  - split-K across blockIdx.y (cps chunks each), ATOMIC => unsafeAtomicAdd
//    into a pre-zeroed output (fp-atomic order noise << bf16 tolerance).
//  - M padded to CoutPad (weights zero-padded), store guarded by co<Cout.
// Block = 256 thr = 4 waves = NSPLIT (pixel split) x MSPLIT (cout split).
// ---------------------------------------------------------------------------
template<int K, int TY, int TX, int NSPLIT, int MSPLIT, int MT, bool VEC4, bool ATOMIC>
__global__ __launch_bounds__(256)
void conv_mfma2(const float* __restrict__ in1, int C1,
                const float* __restrict__ in2, int C2, int Cin,
                const ushort* __restrict__ wt,
                float* __restrict__ outDst,
                int H, int W, int Cout, int CoutPad, int Cin_pad,
                int tilesX, int nchunks, int cps) {
    constexpr int P = K / 2;
    constexpr int XOFF = (K == 1) ? 0 : 4;
    constexpr int JOFF = XOFF - P;
    constexpr int HXs = (TX + K - 1 + JOFF + 3) & ~3;
    constexpr int HY = TY + K - 1;
    constexpr int PITCH = 40;                    // ushorts per pos (32 ci + pad)
    constexpr int KK = K * K;
    constexpr int PXW = TY * TX / NSPLIT;
    constexpr int NT = PXW / 16;
    constexpr int G = HXs / 4;
    constexpr int NITEM = 16 * HY * G;

    __shared__ ushort sT[HY * HXs * PITCH];

    const int tid = threadIdx.x;
    const int lane = tid & 63, wv = tid >> 6;
    const int nwave = wv % NSPLIT, mwave = wv / NSPLIT;
    const int l15 = lane & 15, lg = lane >> 4;

    const int txi = blockIdx.x % tilesX;
    const int tyi = blockIdx.x / tilesX;
    const int b = blockIdx.z;
    const int x0 = txi * TX, y0 = tyi * TY;
    const size_t HW = (size_t)H * W;

    const int co0 = mwave * (MT * 16);

    int posBase[NT], py_[NT], px_[NT];
    #pragma unroll
    for (int nt = 0; nt < NT; ++nt) {
        int pidx = nwave * PXW + nt * 16 + l15;
        int py = pidx / TX, px = pidx % TX;
        py_[nt] = py; px_[nt] = px;
        posBase[nt] = (py * HXs + px + JOFF) * PITCH + lg * 8;
    }
    const int aoff = l15 * Cin_pad + lg * 8;

    f32x4 acc[MT][NT];
    #pragma unroll
    for (int i = 0; i < MT; ++i)
        #pragma unroll
        for (int j = 0; j < NT; ++j) acc[i][j] = (f32x4)0.f;

    const int c0 = blockIdx.y * cps;
    const int c1 = (c0 + cps < nchunks) ? c0 + cps : nchunks;

    for (int c = c0; c < c1; ++c) {
        const int ci0 = c * 32;
        __syncthreads();
        // ---- stage halo tile: [pos][ci] packed pairs ----
        for (int i = tid; i < NITEM; i += 256) {
            int g  = i % G;
            int rr = (i / G) % HY;
            int cp = i / (G * HY);
            int ci = ci0 + cp * 2;
            int y = y0 - P + rr;
            int xg = x0 - XOFF + g * 4;
            ushort* dp = &sT[(rr * HXs + g * 4) * PITCH + cp * 2];
            const float* src; int cbase;
            if (ci < C1) { src = in1; cbase = b * C1 + ci; }
            else         { src = in2; cbase = b * C2 + (ci - C1); }
            const float* p0 = src + (long long)cbase * (long long)HW + (long long)y * W + xg;
            bool fast = VEC4 && (unsigned)y < (unsigned)H && xg >= 0 && (xg + 3) < W && (ci + 1) < Cin;
            if (fast) {
                float4 a  = *(const float4*)p0;
                float4 b2 = *(const float4*)(p0 + HW);
                *(unsigned*)(dp)             = (unsigned)f2bf(a.x) | ((unsigned)f2bf(b2.x) << 16);
                *(unsigned*)(dp + PITCH)     = (unsigned)f2bf(a.y) | ((unsigned)f2bf(b2.y) << 16);
                *(unsigned*)(dp + 2 * PITCH) = (unsigned)f2bf(a.z) | ((unsigned)f2bf(b2.z) << 16);
                *(unsigned*)(dp + 3 * PITCH) = (unsigned)f2bf(a.w) | ((unsigned)f2bf(b2.w) << 16);
            } else {
                #pragma unroll
                for (int u = 0; u < 4; ++u) {
                    int x = xg + u;
                    unsigned pk = 0;
                    if ((unsigned)y < (unsigned)H && (unsigned)x < (unsigned)W && ci < Cin) {
                        float v0 = p0[u];
                        float v1 = (ci + 1 < Cin) ? p0[u + (long long)HW] : 0.f;
                        pk = (unsigned)f2bf(v0) | ((unsigned)f2bf(v1) << 16);
                    }
                    *(unsigned*)(dp + u * PITCH) = pk;
                }
            }
        }
        __syncthreads();

        // ---- A prefetch t=0 ----
        bf16x8 afA[MT];
        {
            const ushort* ap = wt + (size_t)co0 * Cin_pad + ci0 + aoff;
            #pragma unroll
            for (int mt = 0; mt < MT; ++mt)
                afA[mt] = *(const bf16x8*)(ap + (size_t)mt * 16 * Cin_pad);
        }
        #pragma unroll
        for (int t = 0; t < KK; ++t) {
            bf16x8 afB[MT];
            if (t + 1 < KK) {
                const ushort* ap = wt + (size_t)((t + 1) * CoutPad + co0) * Cin_pad + ci0 + aoff;
                #pragma unroll
                for (int mt = 0; mt < MT; ++mt)
                    afB[mt] = *(const bf16x8*)(ap + (size_t)mt * 16 * Cin_pad);
            }
            const int tOff = ((t / K) * HXs + (t % K)) * PITCH;
            bf16x8 bf[NT];
            #pragma unroll
            for (int nt = 0; nt < NT; ++nt)
                bf[nt] = *(const bf16x8*)(sT + posBase[nt] + tOff);
            #pragma unroll
            for (int mt = 0; mt < MT; ++mt)
                #pragma unroll
                for (int nt = 0; nt < NT; ++nt)
                    acc[mt][nt] = __builtin_amdgcn_mfma_f32_16x16x32_bf16(
                        afA[mt], bf[nt], acc[mt][nt], 0, 0, 0);
            if (t + 1 < KK) {
                #pragma unroll
                for (int mt = 0; mt < MT; ++mt) afA[mt] = afB[mt];
            }
        }
    }

    // ---- store ----
    #pragma unroll
    for (int mt = 0; mt < MT; ++mt) {
        #pragma unroll
        for (int nt = 0; nt < NT; ++nt) {
            int y = y0 + py_[nt], x = x0 + px_[nt];
            if (y < H && x < W) {
                #pragma unroll
                for (int r = 0; r < 4; ++r) {
                    int co = co0 + mt * 16 + lg * 4 + r;
                    if (co < Cout) {
                        size_t o = ((size_t)(b * Cout + co)) * HW + (size_t)y * W + x;
                        if (ATOMIC) unsafeAtomicAdd(&outDst[o], acc[mt][nt][r]);
                        else        outDst[o] = acc[mt][nt][r];
                    }
                }
            }
        }
    }
}

// ---------------------------------------------------------------------------
// ConvTranspose2d k3/s2/p1/op1 via MFMA, 4-phase subpixel decomposition.
// ---------------------------------------------------------------------------
template<int TY, int TX, int NSPLIT, int MT>
__global__ __launch_bounds__(256)
void convt_mfma(const float* __restrict__ in,
                const ushort* __restrict__ wtp,
                float* __restrict__ out,
                int Cin, int Cout, int Cin_pad, int Hin, int Win,
                int tilesX, int tilesY) {
    constexpr int HY = TY + 1, HX = TX + 1;
    constexpr int PITCH = 40;
    constexpr int NPX = TY * TX;
    constexpr int PXW = NPX / NSPLIT;
    constexpr int NT = PXW / 16;
    constexpr int NPOS = HY * HX;
    constexpr int NITER = (NPOS * 16 + 255) / 256;

    __shared__ ushort sT[NPOS * PITCH];

    constexpr int toy[9] = {0, 0, 0, 1, 0, 1, 1, 0, 0};
    constexpr int tox[9] = {0, 1, 0, 0, 0, 1, 0, 1, 0};
    constexpr int tph[9] = {0, 1, 1, 2, 2, 3, 3, 3, 3};

    const int tid = threadIdx.x;
    const int lane = tid & 63, wv = tid >> 6;
    const int nwave = wv % NSPLIT, mwave = wv / NSPLIT;
    const int l15 = lane & 15, lg = lane >> 4;

    int tile = blockIdx.x;
    const int txi = tile % tilesX;
    int rem = tile / tilesX;
    const int tyi = rem % tilesY;
    const int b = rem / tilesY;
    const int x0 = txi * TX, y0 = tyi * TY;
    const size_t HWi = (size_t)Hin * Win;
    const int Wo = 2 * Win;
    const size_t HWo = (size_t)4 * HWi;

    const int co0 = mwave * (MT * 16);

    int posBase[NT], py_[NT], px_[NT];
    #pragma unroll
    for (int nt = 0; nt < NT; ++nt) {
        int pidx = nwave * PXW + nt * 16 + l15;
        int py = pidx / TX, px = pidx % TX;
        py_[nt] = py; px_[nt] = px;
        posBase[nt] = (py * HX + px) * PITCH + lg * 8;
    }
    const int aoff = l15 * Cin_pad + lg * 8;

    f32x4 acc[4][MT][NT];
    #pragma unroll
    for (int p = 0; p < 4; ++p)
        #pragma unroll
        for (int i = 0; i < MT; ++i)
            #pragma unroll
            for (int j = 0; j < NT; ++j) acc[p][i][j] = (f32x4)0.f;

    const int nchunks = Cin_pad / 32;
    for (int c = 0; c < nchunks; ++c) {
        const int ci0 = c * 32;
        __syncthreads();
        #pragma unroll
        for (int it = 0; it < NITER; ++it) {
            int idx = it * 256 + tid;
            if (idx < NPOS * 16) {
                int pos = idx % NPOS;
                int cp  = idx / NPOS;
                int hy = pos / HX, hx = pos % HX;
                int y = y0 + hy, x = x0 + hx;
                int ci = ci0 + cp * 2;
                unsigned pk = 0;
                if ((unsigned)y < (unsigned)Hin && (unsigned)x < (unsigned)Win && ci < Cin) {
                    const float* p0 = in + (size_t)(b * Cin + ci) * HWi + (size_t)y * Win + x;
                    float v0 = p0[0];
                    float v1 = (ci + 1 < Cin) ? p0[HWi] : 0.f;
                    pk = (unsigned)f2bf(v0) | ((unsigned)f2bf(v1) << 16);
                }
                *(unsigned*)&sT[pos * PITCH + cp * 2] = pk;
            }
        }
        __syncthreads();

        bf16x8 afA[MT];
        {
            const ushort* ap = wtp + (size_t)co0 * Cin_pad + ci0 + aoff;
            #pragma unroll
            for (int mt = 0; mt < MT; ++mt)
                afA[mt] = *(const bf16x8*)(ap + (size_t)mt * 16 * Cin_pad);
        }
        #pragma unroll
        for (int t = 0; t < 9; ++t) {
            bf16x8 afB[MT];
            if (t + 1 < 9) {
                const ushort* ap = wtp + (size_t)((t + 1) * Cout + co0) * Cin_pad + ci0 + aoff;
                #pragma unroll
                for (int mt = 0; mt < MT; ++mt)
                    afB[mt] = *(const bf16x8*)(ap + (size_t)mt * 16 * Cin_pad);
            }
            const int tOff = (toy[t] * HX + tox[t]) * PITCH;
            bf16x8 bf[NT];
            #pragma unroll
            for (int nt = 0; nt < NT; ++nt)
                bf[nt] = *(const bf16x8*)(sT + posBase[nt] + tOff);
            #pragma unroll
            for (int mt = 0; mt < MT; ++mt)
                #pragma unroll
                for (int nt = 0; nt < NT; ++nt)
                    acc[tph[t]][mt][nt] = __builtin_amdgcn_mfma_f32_16x16x32_bf16(
                        afA[mt], bf[nt], acc[tph[t]][mt][nt], 0, 0, 0);
            if (t + 1 < 9) {
                #pragma unroll
                for (int mt = 0; mt < MT; ++mt) afA[mt] = afB[mt];
            }
        }
    }

    #pragma unroll
    for (int p = 0; p < 4; ++p) {
        const int dy = p >> 1, dx = p & 1;
        #pragma unroll
        for (int mt = 0; mt < MT; ++mt) {
            #pragma unroll
            for (int nt = 0; nt < NT; ++nt) {
                int y = y0 + py_[nt], x = x0 + px_[nt];
                if (y < Hin && x < Win) {
                    #pragma unroll
                    for (int r = 0; r < 4; ++r) {
                        int co = co0 + mt * 16 + lg * 4 + r;
                        out[((size_t)(b * Cout + co)) * HWo + (size_t)(2 * y + dy) * Wo + (2 * x + dx)] =
                            acc[p][mt][nt][r];
                    }
                }
            }
        }
    }
}

// ---------------------------------------------------------------------------
// InstanceNorm stats: one block per (b,c). Biased variance, eps=1e-5.
// ---------------------------------------------------------------------------
__global__ __launch_bounds__(256)
void inorm_stats(const float* __restrict__ x,
                 float* __restrict__ mean,
                 float* __restrict__ istd, int HW) {
    int bc = blockIdx.x;
    const float4* p = (const float4*)(x + (size_t)bc * HW);
    int n4 = HW >> 2;
    float s = 0.f, ss = 0.f;
    for (int i = threadIdx.x; i < n4; i += 256) {
        float4 v = p[i];
        s += v.x + v.y + v.z + v.w;
        ss += v.x * v.x + v.y * v.y + v.z * v.z + v.w * v.w;
    }
    #pragma unroll
    for (int o = 32; o > 0; o >>= 1) {
        s  += __shfl_down(s, o);
        ss += __shfl_down(ss, o);
    }
    __shared__ float sh[4][2];
    int wid = threadIdx.x >> 6, ln = threadIdx.x & 63;
    if (ln == 0) { sh[wid][0] = s; sh[wid][1] = ss; }
    __syncthreads();
    if (threadIdx.x == 0) {
        float S = 0.f, SS = 0.f;
        for (int i = 0; i < 4; ++i) { S += sh[i][0]; SS += sh[i][1]; }
        float m = S / HW;
        float v = SS / HW - m * m;
        v = v > 0.f ? v : 0.f;
        mean[bc] = m;
        istd[bc] = rsqrtf(v + 1e-5f);
    }
}

// ---------------------------------------------------------------------------
// Epilogue: feat = relu((raw - m)*istd) [+ res + br[co]]
// ---------------------------------------------------------------------------
template<bool HAS_RES>
__global__ __launch_bounds__(256)
void epilogue_k(const float* __restrict__ raw,
                const float* __restrict__ mean,
                const float* __restrict__ istd,
                const float* __restrict__ res,
                const float* __restrict__ br,
                float* __restrict__ feat,
                int HW, int Cout, int total4) {
    int i = blockIdx.x * 256 + threadIdx.x;
    if (i >= total4) return;
    int bc = (int)(((long long)i * 4) / HW);
    float m = mean[bc], is = istd[bc];
    float4 r = ((const float4*)raw)[i];
    float4 o;
    o.x = fmaxf((r.x - m) * is, 0.f);
    o.y = fmaxf((r.y - m) * is, 0.f);
    o.z = fmaxf((r.z - m) * is, 0.f);
    o.w = fmaxf((r.w - m) * is, 0.f);
    if (HAS_RES) {
        float bb = br[bc % Cout];
        float4 e = ((const float4*)res)[i];
        o.x += e.x + bb; o.y += e.y + bb; o.z += e.z + bb; o.w += e.w + bb;
    }
    ((float4*)feat)[i] = o;
}

extern "C" void kernel_launch(void* const* d_in, const int* in_sizes, int n_in,
                              void* d_out, int out_size, void* d_ws, size_t ws_size,
                              hipStream_t stream) {
    const float* f4   = (const float*)d_in[0];
    const float* f8   = (const float*)d_in[1];
    const float* f16  = (const float*)d_in[2];
    const float* f32  = (const float*)d_in[3];
    const float* w32  = (const float*)d_in[4];
    const float* wt32 = (const float*)d_in[6];
    const float* w16  = (const float*)d_in[7];
    const float* wr16 = (const float*)d_in[9];
    const float* br16 = (const float*)d_in[10];
    const float* wt16 = (const float*)d_in[11];
    const float* w8   = (const float*)d_in[12];
    const float* wr8  = (const float*)d_in[14];
    const float* br8  = (const float*)d_in[15];
    const float* wt8  = (const float*)d_in[16];
    const float* w4   = (const float*)d_in[17];
    const float* wr4  = (const float*)d_in[19];
    const float* br4  = (const float*)d_in[20];
    // main-conv biases cancel under InstanceNorm -> unused.

    float* out = (float*)d_out;

    const int B = 2, C = 256;
    const int H4 = 160, W4 = 240;
    const int H8 = 80,  W8 = 120;
    const int H16 = 40, W16 = 60;
    const int H32 = 20, W32 = 30;

    float* feat4  = out;
    float* feat8  = out + (size_t)B * 48 * H4 * W4;
    float* feat16 = feat8 + (size_t)B * 64 * H8 * W8;
    float* feat32 = feat16 + (size_t)B * 192 * H16 * W16;

    const size_t bufElems = (size_t)B * 48 * H4 * W4;  // 3,686,400
    float* wsUp   = (float*)d_ws;
    float* wsRaw  = wsUp + bufElems;
    float* stMean = wsRaw + bufElems;
    float* stIstd = stMean + 512;

    // bf16 repacked weights live in the feat4 output region (written last).
    ushort* wb = (ushort*)feat4;
    ushort* W32p = wb;                          // 9*192*256  (Cout padded 160->192)
    ushort* W16p = W32p + 9 * 192 * 256;        // 25*192*448
    ushort* W8p  = W16p + 25 * 192 * 448;       // 25*64*320
    ushort* W4p  = W8p  + 25 * 64 * 320;        // 25*48*320
    ushort* R16p = W4p  + 25 * 48 * 320;        // 192*256
    ushort* R8p  = R16p + 192 * 256;            // 64*256
    ushort* R4p  = R8p  + 64 * 256;             // 48*256
    ushort* T32p = R4p  + 48 * 256;             // 9*192*160
    ushort* T16p = T32p + 9 * 192 * 160;        // 9*64*192
    ushort* T8p  = T16p + 9 * 64 * 192;         // 9*48*64
    // total ~4.0M ushorts = 8.0MB < feat4's 14.7MB.

    // ---- weight repacks ----
    {
        int t1 = 9 * 192 * 256;
        transpose_w<<<cdiv(t1, 256), 256, 0, stream>>>(w32, W32p, 160, 192, 256, 256, 9, t1);
        int t2 = 25 * 192 * 448;
        transpose_w<<<cdiv(t2, 256), 256, 0, stream>>>(w16, W16p, 192, 192, 448, 448, 25, t2);
        int t3 = 25 * 64 * 320;
        transpose_w<<<cdiv(t3, 256), 256, 0, stream>>>(w8, W8p, 64, 64, 320, 320, 25, t3);
        int t4 = 25 * 48 * 320;
        transpose_w<<<cdiv(t4, 256), 256, 0, stream>>>(w4, W4p, 48, 48, 304, 320, 25, t4);
        int t5 = 192 * 256;
        transpose_w<<<cdiv(t5, 256), 256, 0, stream>>>(wr16, R16p, 192, 192, 256, 256, 1, t5);
        int t6 = 64 * 256;
        transpose_w<<<cdiv(t6, 256), 256, 0, stream>>>(wr8, R8p, 64, 64, 256, 256, 1, t6);
        int t7 = 48 * 256;
        transpose_w<<<cdiv(t7, 256), 256, 0, stream>>>(wr4, R4p, 48, 48, 256, 256, 1, t7);
        int u1 = 9 * 192 * 160;
        transpose_wt<<<cdiv(u1, 256), 256, 0, stream>>>(wt32, T32p, 160, 192, 160, u1);
        int u2 = 9 * 64 * 192;
        transpose_wt<<<cdiv(u2, 256), 256, 0, stream>>>(wt16, T16p, 192, 64, 192, u2);
        int u3 = 9 * 48 * 64;
        transpose_wt<<<cdiv(u3, 256), 256, 0, stream>>>(wt8, T8p, 64, 48, 64, u3);
    }

    // ---------------- stage 32 (K=3, Cin=256, Cout=160, 20x30) ----------------
    {
        hipMemsetAsync(wsRaw, 0, (size_t)B * 160 * H32 * W32 * 4, stream);
        int tX = cdiv(W32, 8), tY = cdiv(H32, 4);   // 4 x 5
        dim3 g(tX * tY, 4, B);                       // KSPLIT=4 (2 chunks each)
        conv_mfma2<3, 4, 8, 1, 4, 3, false, true><<<g, 256, 0, stream>>>(
            f32, C, nullptr, 0, C, W32p, wsRaw, H32, W32, 160, 192, 256, tX, 8, 2);
        inorm_stats<<<B * 160, 256, 0, stream>>>(wsRaw, stMean, stIstd, H32 * W32);
        int tot4 = B * 160 * H32 * W32 / 4;
        epilogue_k<false><<<cdiv(tot4, 256), 256, 0, stream>>>(
            wsRaw, stMean, stIstd, nullptr, nullptr, feat32, H32 * W32, 160, tot4);
        int uX = cdiv(W32, 8), uY = cdiv(H32, 2);
        convt_mfma<2, 8, 1, 3><<<uX * uY * B, 256, 0, stream>>>(
            feat32, T32p, wsUp, 160, 192, 160, H32, W32, uX, uY);
    }
    // ---------------- stage 16 (K=5, Cin=256+192, Cout=192, 40x60) ------------
    {
        hipMemsetAsync(wsRaw, 0, (size_t)B * 192 * H16 * W16 * 4, stream);
        hipMemsetAsync(feat16, 0, (size_t)B * 192 * H16 * W16 * 4, stream);
        int tX = cdiv(W16, 8), tY = cdiv(H16, 4);   // 8 x 10
        dim3 g(tX * tY, 7, B);                       // KSPLIT=7 (2 chunks each)
        conv_mfma2<5, 4, 8, 1, 4, 3, true, true><<<g, 256, 0, stream>>>(
            f16, C, wsUp, 192, 448, W16p, wsRaw, H16, W16, 192, 192, 448, tX, 14, 2);
        dim3 gr(tX * tY, 2, B);                      // KSPLIT=2 (4 chunks each)
        conv_mfma2<1, 4, 8, 1, 4, 3, true, true><<<gr, 256, 0, stream>>>(
            f16, C, nullptr, 0, C, R16p, feat16, H16, W16, 192, 192, 256, tX, 8, 4);
        inorm_stats<<<B * 192, 256, 0, stream>>>(wsRaw, stMean, stIstd, H16 * W16);
        int tot4 = B * 192 * H16 * W16 / 4;
        epilogue_k<true><<<cdiv(tot4, 256), 256, 0, stream>>>(
            wsRaw, stMean, stIstd, feat16, br16, feat16, H16 * W16, 192, tot4);
        int uX = cdiv(W16, 8), uY = cdiv(H16, 4);
        convt_mfma<4, 8, 2, 2><<<uX * uY * B, 256, 0, stream>>>(
            feat16, T16p, wsUp, 192, 64, 192, H16, W16, uX, uY);
    }
    // ---------------- stage 8 (K=5, Cin=256+64, Cout=64, 80x120) --------------
    {
        hipMemsetAsync(wsRaw, 0, (size_t)B * 64 * H8 * W8 * 4, stream);
        hipMemsetAsync(feat8, 0, (size_t)B * 64 * H8 * W8 * 4, stream);
        int tX = cdiv(W8, 8), tY = cdiv(H8, 8);     // 15 x 10
        dim3 g(tX * tY, 2, B);                       // KSPLIT=2 (5 chunks each)
        conv_mfma2<5, 8, 8, 2, 2, 2, true, true><<<g, 256, 0, stream>>>(
            f8, C, wsUp, 64, 320, W8p, wsRaw, H8, W8, 64, 64, 320, tX, 10, 5);
        dim3 gr(tX * tY, 2, B);                      // KSPLIT=2 (4 chunks each)
        conv_mfma2<1, 8, 8, 2, 2, 2, true, true><<<gr, 256, 0, stream>>>(
            f8, C, nullptr, 0, C, R8p, feat8, H8, W8, 64, 64, 256, tX, 8, 4);
        inorm_stats<<<B * 64, 256, 0, stream>>>(wsRaw, stMean, stIstd, H8 * W8);
        int tot4 = B * 64 * H8 * W8 / 4;
        epilogue_k<true><<<cdiv(tot4, 256), 256, 0, stream>>>(
            wsRaw, stMean, stIstd, feat8, br8, feat8, H8 * W8, 64, tot4);
        int uX = cdiv(W8, 16), uY = cdiv(H8, 4);
        convt_mfma<4, 16, 4, 3><<<uX * uY * B, 256, 0, stream>>>(
            feat8, T8p, wsUp, 64, 48, 64, H8, W8, uX, uY);
    }
    // ---------------- stage 4 (K=5, Cin=256+48, Cout=48, 160x240) -------------
    {
        int tX = cdiv(W4, 16), tY = cdiv(H4, 8);    // 15 x 20 -> 600 blocks
        dim3 g(tX * tY, 1, B);
        conv_mfma2<5, 8, 16, 4, 1, 3, true, false><<<g, 256, 0, stream>>>(
            f4, C, wsUp, 48, 304, W4p, wsRaw, H4, W4, 48, 48, 320, tX, 10, 10);
        // residual overwrites wsUp (conv4 above already consumed it)
        conv_mfma2<1, 8, 16, 4, 1, 3, true, false><<<g, 256, 0, stream>>>(
            f4, C, nullptr, 0, C, R4p, wsUp, H4, W4, 48, 48, 256, tX, 8, 8);
        inorm_stats<<<B * 48, 256, 0, stream>>>(wsRaw, stMean, stIstd, H4 * W4);
        int tot4 = B * 48 * H4 * W4 / 4;
        epilogue_k<true><<<cdiv(tot4, 256), 256, 0, stream>>>(
            wsRaw, stMean, stIstd, wsUp, br4, feat4, H4 * W4, 48, tot4);
    }
}